// Round 7
// baseline (240.709 us; speedup 1.0000x reference)
//
#include <hip/hip_runtime.h>
#include <hip/hip_bf16.h>

typedef short short8 __attribute__((ext_vector_type(8)));
typedef float f32x4 __attribute__((ext_vector_type(4)));
typedef unsigned uint4v __attribute__((ext_vector_type(4)));

#define F 32
#define NB 4
#define BINSH 5        // 32 nodes per dst-bin
#define BINSZ 32
#define EPB 512        // edges per Phase-A block
#define SCH 4096       // edges per scatter block
#define MAXBIN 2048
// old path constants
#define OSCH 2048
#define OMAXNBLK 1024

__device__ __forceinline__ short f2bf(float f) {   // RNE f32->bf16
    unsigned u = __float_as_uint(f);
    unsigned r = (u + 0x7FFFu + ((u >> 16) & 1u)) >> 16;
    return (short)r;
}

__device__ __forceinline__ unsigned pk2(float a, float b) {  // packed bf16 pair
    __hip_bfloat162 h = __float22bfloat162_rn(make_float2(a, b));
    union { __hip_bfloat162 h; unsigned u; } cv; cv.h = h; return cv.u;
}

// -------- weight prep: bf16 B-fragment layout into ws (32 KB, L2-resident) --
__global__ __launch_bounds__(256) void w_prep(
    const float* __restrict__ w, short* __restrict__ wbf)
{
    int idx = blockIdx.x * 256 + threadIdx.x;   // 64 x 256 = 16384
    int k = idx >> 10, rem = idx & 1023, i = rem >> 5, o = rem & 31;
    int slot = (((k * 4 + (i >> 3)) * 2 + (o >> 4)) * 16 + (o & 15)) * 8 + (i & 7);
    wbf[slot] = f2bf(w[idx]);
}

// -------- combined hist: dst-bin (LDS) + cell (LDS), flush to global --------
__global__ __launch_bounds__(256) void h2_kernel(
    const int* __restrict__ ei, const float* __restrict__ attr, int E, int nbin,
    int* __restrict__ bincnt, int* __restrict__ cellcnt)
{
    __shared__ int hb[MAXBIN];
    __shared__ int hc[9];
    int t = threadIdx.x;
    for (int i = t; i < nbin; i += 256) hb[i] = 0;
    if (t < 9) hc[t] = 0;
    __syncthreads();
    int stride = gridDim.x * blockDim.x;
    for (int e = blockIdx.x * blockDim.x + t; e < E; e += stride) {
        int dst = ei[e];
        float2 a = reinterpret_cast<const float2*>(attr)[e];
        float tx = fminf(fmaxf((a.x + 1.0f) * 1.5f, 0.f), 3.f);
        float ty = fminf(fmaxf((a.y + 1.0f) * 1.5f, 0.f), 3.f);
        int kx = min((int)tx, 2), ky = min((int)ty, 2);
        atomicAdd(&hb[dst >> BINSH], 1);
        atomicAdd(&hc[kx * 3 + ky], 1);
    }
    __syncthreads();
    for (int i = t; i < nbin; i += 256)
        if (hb[i]) atomicAdd(&bincnt[i], hb[i]);
    if (t < 9 && hc[t]) atomicAdd(&cellcnt[t], hc[t]);
}

// -------- scan: bins -> binbase/bincur ; cells -> cellbase/cellcur/blkoff ---
__global__ __launch_bounds__(256) void scan2_kernel(
    const int* __restrict__ bincnt, int* __restrict__ binbase,
    int* __restrict__ bincur, const int* __restrict__ cellcnt,
    int* __restrict__ cellbase, int* __restrict__ cellcur,
    int* __restrict__ blkoff, int nbin)
{
    __shared__ int part[256];
    int t = threadIdx.x;
    int chunk = (nbin + 255) / 256;
    int lo = t * chunk, hi = min(lo + chunk, nbin);
    int s = 0;
    for (int q = lo; q < hi; ++q) s += bincnt[q];
    part[t] = s;
    __syncthreads();
    if (t == 0) {
        int run = 0;
        for (int j = 0; j < 256; ++j) { int v = part[j]; part[j] = run; run += v; }
        binbase[nbin] = run;
    }
    __syncthreads();
    int run = part[t];
    for (int q = lo; q < hi; ++q) {
        binbase[q] = run; bincur[q] = run;
        run += bincnt[q];
    }
    if (t == 0) {
        int off = 0, boff = 0;
        for (int c = 0; c < 9; ++c) {
            cellbase[c] = off; cellcur[c] = off; blkoff[c] = boff;
            off  += cellcnt[c];
            boff += (cellcnt[c] + EPB - 1) / EPB;
        }
        cellbase[9] = off; blkoff[9] = boff;
    }
}

// -------- scatter: both orderings in one pass -------------------------------
// cellrec[poscell] = {src, posdst, tx_f32, ty_f32}; dloc8[posdst] = dst&31
__global__ __launch_bounds__(256) void scat2_kernel(
    const int* __restrict__ ei, const float* __restrict__ attr, int E, int nbin,
    int* __restrict__ bincur, int* __restrict__ cellcur,
    uint4* __restrict__ cellrec, unsigned char* __restrict__ dloc8)
{
    __shared__ int hb[MAXBIN];
    __shared__ int hc[9];
    int t = threadIdx.x, b = blockIdx.x;
    int start = b * SCH, end = min(start + SCH, E);
    for (int i = t; i < nbin; i += 256) hb[i] = 0;
    if (t < 9) hc[t] = 0;
    __syncthreads();
    for (int e = start + t; e < end; e += 256) {
        int dst = ei[e];
        float2 a = reinterpret_cast<const float2*>(attr)[e];
        float tx = fminf(fmaxf((a.x + 1.0f) * 1.5f, 0.f), 3.f);
        float ty = fminf(fmaxf((a.y + 1.0f) * 1.5f, 0.f), 3.f);
        int kx = min((int)tx, 2), ky = min((int)ty, 2);
        atomicAdd(&hb[dst >> BINSH], 1);
        atomicAdd(&hc[kx * 3 + ky], 1);
    }
    __syncthreads();
    for (int k = t; k < nbin; k += 256) {
        int c = hb[k];
        if (c) hb[k] = atomicAdd(&bincur[k], c);
    }
    if (t < 9) hc[t] = atomicAdd(&cellcur[t], hc[t]);
    __syncthreads();
    for (int e = start + t; e < end; e += 256) {
        int dst = ei[e];
        int src = ei[E + e];
        float2 a = reinterpret_cast<const float2*>(attr)[e];
        float tx = fminf(fmaxf((a.x + 1.0f) * 1.5f, 0.f), 3.f);
        float ty = fminf(fmaxf((a.y + 1.0f) * 1.5f, 0.f), 3.f);
        int kx = min((int)tx, 2), ky = min((int)ty, 2);
        int pd = atomicAdd(&hb[dst >> BINSH], 1);
        int pc = atomicAdd(&hc[kx * 3 + ky], 1);
        uint4 rec;
        rec.x = (unsigned)src;
        rec.y = (unsigned)pd;
        rec.z = __float_as_uint(tx);
        rec.w = __float_as_uint(ty);
        cellrec[pc] = rec;
        dloc8[pd] = (unsigned char)(dst & (BINSZ - 1));
    }
}

// -------- Phase A: cell-sorted tiles -> per-edge messages (plain stores) ----
__global__ __launch_bounds__(256, 4) void bconv_msg(
    const float* __restrict__ x_j, const short* __restrict__ wbf,
    const int* __restrict__ cellbase, const int* __restrict__ blkoff,
    const uint4* __restrict__ cellrec, float* __restrict__ msg)
{
    int b = blockIdx.x;
    if (b >= blkoff[9]) return;
    int c = 0;
    #pragma unroll
    for (int q = 1; q < 9; ++q) c += (b >= blkoff[q]) ? 1 : 0;
    int kx0 = c / 3, ky0 = c - 3 * (c / 3);
    int local  = b - blkoff[c];
    int cstart = cellbase[c], cend = cellbase[c + 1];
    int pstart = cstart + local * EPB;
    int pend   = min(pstart + EPB, cend);
    if (pstart >= pend) return;

    int t = threadIdx.x;
    int wid = t >> 6, lane = t & 63;
    int row16 = lane & 15, hi = lane >> 4;

    // B fragments for this cell (8 x 16B loads from L2-resident wbf)
    short8 w0[4], w1[4];
    #pragma unroll
    for (int kk = 0; kk < 4; ++kk) {
        int ks = (kx0 + (kk >> 1)) * NB + (ky0 + (kk & 1));
        w0[kk] = *reinterpret_cast<const short8*>(
            wbf + (((ks * 4 + hi) * 2 + 0) * 16 + row16) * 8);
        w1[kk] = *reinterpret_cast<const short8*>(
            wbf + (((ks * 4 + hi) * 2 + 1) * 16 + row16) * 8);
    }

    const float4* x4 = reinterpret_cast<const float4*>(x_j);
    int ntile = (pend - pstart + 15) >> 4;

    auto fetch = [&](int ti, uint4& rec, float4& fa, float4& fb, int& pdv) {
        int p = pstart + ti * 16 + row16;
        bool v = p < pend;
        int pp = v ? p : pstart;
        rec = cellrec[pp];
        int src = rec.x;
        fa = x4[src * 8 + 2 * hi];
        fb = x4[src * 8 + 2 * hi + 1];
        pdv = v ? (int)rec.y : -1;
    };

    int it = wid;
    uint4 rec; float4 fa, fb; int pdv;
    if (it < ntile) fetch(it, rec, fa, fb, pdv);

    for (; it < ntile; it += 4) {
        uint4 recN; float4 faN, fbN; int pdvN = -1;
        bool hn = (it + 4) < ntile;
        if (hn) fetch(it + 4, recN, faN, fbN, pdvN);   // loads fly under compute

        float tx = __uint_as_float(rec.z), ty = __uint_as_float(rec.w);
        float fx = tx - (float)kx0, fy = ty - (float)ky0;
        float bx0 = 1.f - fx, by0 = 1.f - fy;
        float bc[4] = { bx0 * by0, bx0 * fy, fx * by0, fx * fy };
        float fl[8] = { fa.x, fa.y, fa.z, fa.w, fb.x, fb.y, fb.z, fb.w };

        f32x4 a0 = {0,0,0,0}, a1 = {0,0,0,0};
        #pragma unroll
        for (int kk = 0; kk < 4; ++kk) {
            float s = bc[kk];
            uint4v u;
            u[0] = pk2(fl[0] * s, fl[1] * s);
            u[1] = pk2(fl[2] * s, fl[3] * s);
            u[2] = pk2(fl[4] * s, fl[5] * s);
            u[3] = pk2(fl[6] * s, fl[7] * s);
            short8 av = __builtin_bit_cast(short8, u);
            a0 = __builtin_amdgcn_mfma_f32_16x16x32_bf16(av, w0[kk], a0, 0, 0, 0);
            a1 = __builtin_amdgcn_mfma_f32_16x16x32_bf16(av, w1[kk], a1, 0, 0, 0);
        }
        // C row r = edge 4*hi+r ; col = row16 (+16). Plain stores to msg row.
        #pragma unroll
        for (int r = 0; r < 4; ++r) {
            int pd = __shfl(pdv, 4 * hi + r, 64);
            if (pd >= 0) {
                float* mrow = msg + (size_t)pd * 32;
                mrow[row16]      = a0[r];
                mrow[row16 + 16] = a1[r];
            }
        }
        rec = recN; fa = faN; fb = fbN; pdv = pdvN;
    }
}

// -------- Phase B: per-bin streaming reduce (LDS atomics, no global atomics)
__global__ __launch_bounds__(256, 8) void bconv_reduce(
    const float* __restrict__ msg, const unsigned char* __restrict__ dloc8,
    const int* __restrict__ binbase, float* __restrict__ out, int N)
{
    __shared__ float acc[BINSZ][33];
    int t = threadIdx.x, bin = blockIdx.x;
    for (int i = t; i < BINSZ * 33; i += 256) (&acc[0][0])[i] = 0.f;
    __syncthreads();

    int s0 = binbase[bin], s1 = binbase[bin + 1];
    int col = t & 31;
    int i = s0 + (t >> 5);
    for (; i + 24 < s1; i += 32) {              // 4x unroll, coalesced 1KB/step
        float v0 = msg[(size_t)(i)      * 32 + col];
        float v1 = msg[(size_t)(i + 8)  * 32 + col];
        float v2 = msg[(size_t)(i + 16) * 32 + col];
        float v3 = msg[(size_t)(i + 24) * 32 + col];
        int d0 = dloc8[i], d1 = dloc8[i + 8], d2 = dloc8[i + 16], d3 = dloc8[i + 24];
        atomicAdd(&acc[d0][col], v0);
        atomicAdd(&acc[d1][col], v1);
        atomicAdd(&acc[d2][col], v2);
        atomicAdd(&acc[d3][col], v3);
    }
    for (; i < s1; i += 8) {
        float v = msg[(size_t)i * 32 + col];
        atomicAdd(&acc[dloc8[i]][col], v);
    }
    __syncthreads();

    int nloc = t >> 3, c4 = (t & 7) * 4;
    int node = bin * BINSZ + nloc;
    if (node < N) {
        float4 v;
        v.x = acc[nloc][c4];     v.y = acc[nloc][c4 + 1];
        v.z = acc[nloc][c4 + 2]; v.w = acc[nloc][c4 + 3];
        *reinterpret_cast<float4*>(&out[(size_t)node * F + c4]) = v;
    }
}

// ====================== FALLBACK 1 (R3 path): cell sort + global atomics ====
__global__ __launch_bounds__(256) void hist_kernel(
    const float* __restrict__ attr, int E, int* __restrict__ counts)
{
    __shared__ int hh[9];
    int b = blockIdx.x, t = threadIdx.x;
    if (t < 9) hh[t] = 0;
    __syncthreads();
    int start = b * OSCH, end = min(start + OSCH, E);
    for (int e = start + t; e < end; e += 256) {
        float2 a = reinterpret_cast<const float2*>(attr)[e];
        float tx = fminf(fmaxf((a.x + 1.0f) * 1.5f, 0.f), 3.f);
        float ty = fminf(fmaxf((a.y + 1.0f) * 1.5f, 0.f), 3.f);
        atomicAdd(&hh[min((int)tx, 2) * 3 + min((int)ty, 2)], 1);
    }
    __syncthreads();
    if (t < 9) counts[b * 9 + t] = hh[t];
}

__global__ __launch_bounds__(512) void scan_kernel(
    int* __restrict__ ws, int* __restrict__ counts, int nblk)
{
    __shared__ int s[OMAXNBLK * 9];
    __shared__ int tot[9];
    __shared__ int coff[9];
    int n = nblk * 9;
    for (int i = threadIdx.x; i < n; i += 512) s[i] = counts[i];
    __syncthreads();
    if (threadIdx.x < 9) {
        int c = threadIdx.x, run = 0;
        for (int b = 0; b < nblk; ++b) {
            int v = s[b * 9 + c];
            s[b * 9 + c] = run;
            run += v;
        }
        tot[c] = run;
    }
    __syncthreads();
    if (threadIdx.x == 0) {
        int off = 0, boff = 0;
        for (int c = 0; c < 9; ++c) {
            ws[c] = off;  coff[c] = off;
            ws[16 + c] = boff;
            off  += tot[c];
            boff += (tot[c] + EPB - 1) / EPB;
        }
        ws[9] = off;
        ws[16 + 9] = boff;
    }
    __syncthreads();
    for (int i = threadIdx.x; i < n; i += 512)
        counts[i] = s[i] + coff[i % 9];
}

__global__ __launch_bounds__(256) void scatter_kernel(
    const float* __restrict__ attr, int E,
    const int* __restrict__ bases, int* __restrict__ sorted)
{
    __shared__ int cur[9];
    int b = blockIdx.x, t = threadIdx.x;
    if (t < 9) cur[t] = bases[b * 9 + t];
    __syncthreads();
    int start = b * OSCH, end = min(start + OSCH, E);
    for (int e = start + t; e < end; e += 256) {
        float2 a = reinterpret_cast<const float2*>(attr)[e];
        float tx = fminf(fmaxf((a.x + 1.0f) * 1.5f, 0.f), 3.f);
        float ty = fminf(fmaxf((a.y + 1.0f) * 1.5f, 0.f), 3.f);
        int c = min((int)tx, 2) * 3 + min((int)ty, 2);
        int pos = atomicAdd(&cur[c], 1);
        sorted[pos] = e;
    }
}

__global__ __launch_bounds__(256) void bconv_mfma(
    const float* __restrict__ x_j, const int* __restrict__ ei,
    const float* __restrict__ attr, const float* __restrict__ weight,
    const int* __restrict__ ws, const int* __restrict__ sorted,
    float* __restrict__ out, int E)
{
    int b = blockIdx.x;
    const int* blkoff = ws + 16;
    if (b >= blkoff[9]) return;
    int c = 0;
    #pragma unroll
    for (int q = 1; q < 9; ++q) c += (b >= blkoff[q]) ? 1 : 0;
    int kx0 = c / 3, ky0 = c - 3 * (c / 3);
    int local  = b - blkoff[c];
    int cstart = ws[c], cend = ws[c + 1];
    int pstart = cstart + local * EPB;
    int pend   = min(pstart + EPB, cend);

    int t = threadIdx.x;
    int wid = t >> 6, lane = t & 63;
    int row16 = lane & 15, hi = lane >> 4;

    short8 wb[4][2];
    #pragma unroll
    for (int kk = 0; kk < 4; ++kk) {
        int ks = (kx0 + (kk >> 1)) * NB + (ky0 + (kk & 1));
        const float* wp = weight + (size_t)ks * F * F;
        #pragma unroll
        for (int n = 0; n < 2; ++n) {
            short8 v;
            #pragma unroll
            for (int j = 0; j < 8; ++j)
                v[j] = f2bf(wp[(8 * hi + j) * F + row16 + 16 * n]);
            wb[kk][n] = v;
        }
    }

    int wstart = pstart + wid * (EPB / 4);
    int wend   = min(wstart + (EPB / 4), pend);
    if (wstart >= wend) return;

    int ntiles = (wend - wstart + 15) >> 4;
    for (int tt = 0; tt < ntiles; ++tt) {
        int p = wstart + tt * 16 + row16;
        bool v = p < wend;
        int pp = v ? p : wstart;
        int e  = sorted[pp];
        int dst = ei[e];
        int srcn = ei[E + e];
        float2 a = reinterpret_cast<const float2*>(attr)[e];
        const float4* xr = reinterpret_cast<const float4*>(x_j + (size_t)srcn * F);
        float4 fa = xr[2 * hi];
        float4 fb = xr[2 * hi + 1];

        float fx = (a.x + 1.0f) * 1.5f - (float)kx0;
        float fy = (a.y + 1.0f) * 1.5f - (float)ky0;
        float vs = v ? 1.f : 0.f;
        float bx0 = (1.f - fx) * vs, bx1 = fx * vs;
        float bc[4] = { bx0 * (1.f - fy), bx0 * fy, bx1 * (1.f - fy), bx1 * fy };

        f32x4 a0 = {0,0,0,0}, a1 = {0,0,0,0};
        #pragma unroll
        for (int kk = 0; kk < 4; ++kk) {
            float s = bc[kk];
            uint4v u;
            u[0] = pk2(fa.x * s, fa.y * s);
            u[1] = pk2(fa.z * s, fa.w * s);
            u[2] = pk2(fb.x * s, fb.y * s);
            u[3] = pk2(fb.z * s, fb.w * s);
            short8 av = __builtin_bit_cast(short8, u);
            a0 = __builtin_amdgcn_mfma_f32_16x16x32_bf16(av, wb[kk][0], a0, 0, 0, 0);
            a1 = __builtin_amdgcn_mfma_f32_16x16x32_bf16(av, wb[kk][1], a1, 0, 0, 0);
        }
        #pragma unroll
        for (int r = 0; r < 4; ++r) {
            int d = __shfl(v ? dst : -1, 4 * hi + r, 64);
            if (d >= 0) {
                atomicAdd(&out[(size_t)d * F + row16],      a0[r]);
                atomicAdd(&out[(size_t)d * F + 16 + row16], a1[r]);
            }
        }
    }
}

// ====================== FALLBACK 2: f32 VALU path ===========================
__global__ __launch_bounds__(256) void bconv_fallback(
    const float* __restrict__ x_j, const int* __restrict__ ei,
    const float* __restrict__ attr, const float* __restrict__ weight,
    float* __restrict__ out, int E)
{
    __shared__ float wl[16 * F * F];
    __shared__ float featl[8][F];
    for (int idx = threadIdx.x; idx < 4096; idx += 256)
        reinterpret_cast<float4*>(wl)[idx] = reinterpret_cast<const float4*>(weight)[idx];
    __syncthreads();

    int lane = threadIdx.x & 31, eslot = threadIdx.x >> 5;
    for (int p = blockIdx.x * 8 + eslot; p < E; p += gridDim.x * 8) {
        int dst = ei[p], srcn = ei[E + p];
        float ax = attr[2 * p], ay = attr[2 * p + 1];
        featl[eslot][lane] = x_j[(size_t)srcn * F + lane];
        float tx = (ax + 1.0f) * 1.5f, ty = (ay + 1.0f) * 1.5f;
        int kx0 = min(max((int)tx, 0), 2), ky0 = min(max((int)ty, 0), 2);
        float fx = tx - kx0, fy = ty - ky0;
        float bcv[4] = { (1.0f - fx) * (1.0f - fy), (1.0f - fx) * fy,
                         fx * (1.0f - fy), fx * fy };
        float msg = 0.f;
        const float4* f4 = reinterpret_cast<const float4*>(&featl[eslot][0]);
        #pragma unroll
        for (int kk = 0; kk < 4; ++kk) {
            int k = (kx0 + (kk >> 1)) * NB + (ky0 + (kk & 1));
            const float* wk = wl + k * F * F;
            float a2 = 0.f;
            #pragma unroll
            for (int j = 0; j < 8; ++j) {
                float4 f = f4[j];
                a2 = fmaf(f.x, wk[(4 * j + 0) * F + lane], a2);
                a2 = fmaf(f.y, wk[(4 * j + 1) * F + lane], a2);
                a2 = fmaf(f.z, wk[(4 * j + 2) * F + lane], a2);
                a2 = fmaf(f.w, wk[(4 * j + 3) * F + lane], a2);
            }
            msg = fmaf(bcv[kk], a2, msg);
        }
        atomicAdd(&out[(size_t)dst * F + lane], msg);
    }
}

extern "C" void kernel_launch(void* const* d_in, const int* in_sizes, int n_in,
                              void* d_out, int out_size, void* d_ws, size_t ws_size,
                              hipStream_t stream) {
    const float* x_j    = (const float*)d_in[1];
    const int*   ei     = (const int*)d_in[2];
    const float* attr   = (const float*)d_in[3];
    const float* weight = (const float*)d_in[4];
    float* out = (float*)d_out;
    int E = in_sizes[2] / 2;
    int N = in_sizes[0] / F;

    int nbin = (N + BINSZ - 1) >> BINSH;

    // --- new-path ws layout (ints) ---
    int o_bincnt   = 0;                       // nbin
    int o_cellcnt  = o_bincnt + nbin;         // 9   (memset covers bincnt+cellcnt)
    int o_binbase  = o_cellcnt + 9;           // nbin+1
    int o_bincur   = o_binbase + nbin + 1;    // nbin
    int o_cellbase = o_bincur + nbin;         // 10
    int o_cellcur  = o_cellbase + 10;         // 9
    int o_blkoff   = o_cellcur + 9;           // 10
    int o_wbf      = (o_blkoff + 10 + 3) & ~3;          // 8192 ints
    int o_dloc     = o_wbf + 8192;                      // ceil(E/4) ints
    int o_cellrec  = (o_dloc + (E + 3) / 4 + 3) & ~3;   // 4E ints (uint4)
    size_t o_msg   = (size_t)((o_cellrec + 4 * (size_t)E + 3) & ~3);
    size_t need_new = (o_msg + 32 * (size_t)E) * sizeof(int);

    // --- old-path ws layout ---
    int nblk_sort = (E + OSCH - 1) / OSCH;
    int sorted_off = 32 + ((nblk_sort * 9 + 15) & ~15);
    size_t need_old = (size_t)(sorted_off + E) * sizeof(int);

    if (nbin <= MAXBIN && N <= 65536 && E < (1 << 24) && ws_size >= need_new) {
        int* ws = (int*)d_ws;
        short* wbf = (short*)(ws + o_wbf);
        unsigned char* dloc8 = (unsigned char*)(ws + o_dloc);
        uint4* cellrec = (uint4*)(ws + o_cellrec);
        float* msg = (float*)(ws + o_msg);

        hipMemsetAsync(ws, 0, (size_t)(nbin + 9) * sizeof(int), stream);
        w_prep<<<64, 256, 0, stream>>>(weight, wbf);
        h2_kernel<<<256, 256, 0, stream>>>(ei, attr, E, nbin,
                                           ws + o_bincnt, ws + o_cellcnt);
        scan2_kernel<<<1, 256, 0, stream>>>(ws + o_bincnt, ws + o_binbase,
                                            ws + o_bincur, ws + o_cellcnt,
                                            ws + o_cellbase, ws + o_cellcur,
                                            ws + o_blkoff, nbin);
        scat2_kernel<<<(E + SCH - 1) / SCH, 256, 0, stream>>>(
            ei, attr, E, nbin, ws + o_bincur, ws + o_cellcur, cellrec, dloc8);
        int nblkA = (E + EPB - 1) / EPB + 9;
        bconv_msg<<<nblkA, 256, 0, stream>>>(x_j, wbf, ws + o_cellbase,
                                             ws + o_blkoff, cellrec, msg);
        bconv_reduce<<<nbin, 256, 0, stream>>>(msg, dloc8, ws + o_binbase, out, N);
    } else if (nblk_sort <= OMAXNBLK && ws_size >= need_old) {
        hipMemsetAsync(d_out, 0, (size_t)out_size * sizeof(float), stream);
        int* ws      = (int*)d_ws;
        int* counts  = ws + 32;
        int* sorted  = ws + sorted_off;
        hist_kernel<<<nblk_sort, 256, 0, stream>>>(attr, E, counts);
        scan_kernel<<<1, 512, 0, stream>>>(ws, counts, nblk_sort);
        scatter_kernel<<<nblk_sort, 256, 0, stream>>>(attr, E, counts, sorted);
        int nblk_main = (E + EPB - 1) / EPB + 9;
        bconv_mfma<<<nblk_main, 256, 0, stream>>>(x_j, ei, attr, weight, ws, sorted, out, E);
    } else {
        hipMemsetAsync(d_out, 0, (size_t)out_size * sizeof(float), stream);
        bconv_fallback<<<2048, 256, 0, stream>>>(x_j, ei, attr, weight, out, E);
    }
}

// Round 8
// 239.288 us; speedup vs baseline: 1.0059x; 1.0059x over previous
//
#include <hip/hip_runtime.h>
#include <hip/hip_bf16.h>

typedef short short8 __attribute__((ext_vector_type(8)));
typedef float f32x4 __attribute__((ext_vector_type(4)));
typedef unsigned uint4v __attribute__((ext_vector_type(4)));

#define F 32
#define NB 4
#define BINSH 5        // 32 nodes per dst-bin
#define BINSZ 32
#define EPB 512        // edges per Phase-A block
#define SCH 4096       // edges per scatter block
#define MAXBIN 2048
// old path constants
#define OSCH 2048
#define OMAXNBLK 1024

__device__ __forceinline__ short f2bf(float f) {   // RNE f32->bf16
    unsigned u = __float_as_uint(f);
    unsigned r = (u + 0x7FFFu + ((u >> 16) & 1u)) >> 16;
    return (short)r;
}

__device__ __forceinline__ unsigned pk2(float a, float b) {  // packed bf16 pair
    __hip_bfloat162 h = __float22bfloat162_rn(make_float2(a, b));
    union { __hip_bfloat162 h; unsigned u; } cv; cv.h = h; return cv.u;
}

// -------- weight prep: bf16 B-fragment layout into ws (32 KB, L2-resident) --
__global__ __launch_bounds__(256) void w_prep(
    const float* __restrict__ w, short* __restrict__ wbf)
{
    int idx = blockIdx.x * 256 + threadIdx.x;   // 64 x 256 = 16384
    int k = idx >> 10, rem = idx & 1023, i = rem >> 5, o = rem & 31;
    int slot = (((k * 4 + (i >> 3)) * 2 + (o >> 4)) * 16 + (o & 15)) * 8 + (i & 7);
    wbf[slot] = f2bf(w[idx]);
}

// -------- combined hist: dst-bin (LDS) + cell (LDS), flush to global --------
__global__ __launch_bounds__(256) void h2_kernel(
    const int* __restrict__ ei, const float* __restrict__ attr, int E, int nbin,
    int* __restrict__ bincnt, int* __restrict__ cellcnt)
{
    __shared__ int hb[MAXBIN];
    __shared__ int hc[9];
    int t = threadIdx.x;
    for (int i = t; i < nbin; i += 256) hb[i] = 0;
    if (t < 9) hc[t] = 0;
    __syncthreads();
    int stride = gridDim.x * blockDim.x;
    for (int e = blockIdx.x * blockDim.x + t; e < E; e += stride) {
        int dst = ei[e];
        float2 a = reinterpret_cast<const float2*>(attr)[e];
        float tx = fminf(fmaxf((a.x + 1.0f) * 1.5f, 0.f), 3.f);
        float ty = fminf(fmaxf((a.y + 1.0f) * 1.5f, 0.f), 3.f);
        int kx = min((int)tx, 2), ky = min((int)ty, 2);
        atomicAdd(&hb[dst >> BINSH], 1);
        atomicAdd(&hc[kx * 3 + ky], 1);
    }
    __syncthreads();
    for (int i = t; i < nbin; i += 256)
        if (hb[i]) atomicAdd(&bincnt[i], hb[i]);
    if (t < 9 && hc[t]) atomicAdd(&cellcnt[t], hc[t]);
}

// -------- scan: bins -> binbase/bincur ; cells -> cellbase/cellcur/blkoff ---
__global__ __launch_bounds__(256) void scan2_kernel(
    const int* __restrict__ bincnt, int* __restrict__ binbase,
    int* __restrict__ bincur, const int* __restrict__ cellcnt,
    int* __restrict__ cellbase, int* __restrict__ cellcur,
    int* __restrict__ blkoff, int nbin)
{
    __shared__ int part[256];
    int t = threadIdx.x;
    int chunk = (nbin + 255) / 256;
    int lo = t * chunk, hi = min(lo + chunk, nbin);
    int s = 0;
    for (int q = lo; q < hi; ++q) s += bincnt[q];
    part[t] = s;
    __syncthreads();
    if (t == 0) {
        int run = 0;
        for (int j = 0; j < 256; ++j) { int v = part[j]; part[j] = run; run += v; }
        binbase[nbin] = run;
    }
    __syncthreads();
    int run = part[t];
    for (int q = lo; q < hi; ++q) {
        binbase[q] = run; bincur[q] = run;
        run += bincnt[q];
    }
    if (t == 0) {
        int off = 0, boff = 0;
        for (int c = 0; c < 9; ++c) {
            cellbase[c] = off; cellcur[c] = off; blkoff[c] = boff;
            off  += cellcnt[c];
            boff += (cellcnt[c] + EPB - 1) / EPB;
        }
        cellbase[9] = off; blkoff[9] = boff;
    }
}

// -------- scatter: both orderings in one pass -------------------------------
// cellrec[poscell] = {src, posdst, tx_f32, ty_f32}; dloc8[posdst] = dst&31
__global__ __launch_bounds__(256) void scat2_kernel(
    const int* __restrict__ ei, const float* __restrict__ attr, int E, int nbin,
    int* __restrict__ bincur, int* __restrict__ cellcur,
    uint4* __restrict__ cellrec, unsigned char* __restrict__ dloc8)
{
    __shared__ int hb[MAXBIN];
    __shared__ int hc[9];
    int t = threadIdx.x, b = blockIdx.x;
    int start = b * SCH, end = min(start + SCH, E);
    for (int i = t; i < nbin; i += 256) hb[i] = 0;
    if (t < 9) hc[t] = 0;
    __syncthreads();
    for (int e = start + t; e < end; e += 256) {
        int dst = ei[e];
        float2 a = reinterpret_cast<const float2*>(attr)[e];
        float tx = fminf(fmaxf((a.x + 1.0f) * 1.5f, 0.f), 3.f);
        float ty = fminf(fmaxf((a.y + 1.0f) * 1.5f, 0.f), 3.f);
        int kx = min((int)tx, 2), ky = min((int)ty, 2);
        atomicAdd(&hb[dst >> BINSH], 1);
        atomicAdd(&hc[kx * 3 + ky], 1);
    }
    __syncthreads();
    for (int k = t; k < nbin; k += 256) {
        int c = hb[k];
        if (c) hb[k] = atomicAdd(&bincur[k], c);
    }
    if (t < 9) hc[t] = atomicAdd(&cellcur[t], hc[t]);
    __syncthreads();
    for (int e = start + t; e < end; e += 256) {
        int dst = ei[e];
        int src = ei[E + e];
        float2 a = reinterpret_cast<const float2*>(attr)[e];
        float tx = fminf(fmaxf((a.x + 1.0f) * 1.5f, 0.f), 3.f);
        float ty = fminf(fmaxf((a.y + 1.0f) * 1.5f, 0.f), 3.f);
        int kx = min((int)tx, 2), ky = min((int)ty, 2);
        int pd = atomicAdd(&hb[dst >> BINSH], 1);
        int pc = atomicAdd(&hc[kx * 3 + ky], 1);
        uint4 rec;
        rec.x = (unsigned)src;
        rec.y = (unsigned)pd;
        rec.z = __float_as_uint(tx);
        rec.w = __float_as_uint(ty);
        cellrec[pc] = rec;
        dloc8[pd] = (unsigned char)(dst & (BINSZ - 1));
    }
}

// -------- Phase A: cell-sorted tiles -> per-edge messages (plain stores) ----
__global__ __launch_bounds__(256, 4) void bconv_msg(
    const float* __restrict__ x_j, const short* __restrict__ wbf,
    const int* __restrict__ cellbase, const int* __restrict__ blkoff,
    const uint4* __restrict__ cellrec, float* __restrict__ msg)
{
    int b = blockIdx.x;
    if (b >= blkoff[9]) return;
    int c = 0;
    #pragma unroll
    for (int q = 1; q < 9; ++q) c += (b >= blkoff[q]) ? 1 : 0;
    int kx0 = c / 3, ky0 = c - 3 * (c / 3);
    int local  = b - blkoff[c];
    int cstart = cellbase[c], cend = cellbase[c + 1];
    int pstart = cstart + local * EPB;
    int pend   = min(pstart + EPB, cend);
    if (pstart >= pend) return;

    int t = threadIdx.x;
    int wid = t >> 6, lane = t & 63;
    int row16 = lane & 15, hi = lane >> 4;

    // B fragments for this cell (8 x 16B loads from L2-resident wbf)
    short8 w0[4], w1[4];
    #pragma unroll
    for (int kk = 0; kk < 4; ++kk) {
        int ks = (kx0 + (kk >> 1)) * NB + (ky0 + (kk & 1));
        w0[kk] = *reinterpret_cast<const short8*>(
            wbf + (((ks * 4 + hi) * 2 + 0) * 16 + row16) * 8);
        w1[kk] = *reinterpret_cast<const short8*>(
            wbf + (((ks * 4 + hi) * 2 + 1) * 16 + row16) * 8);
    }

    const float4* x4 = reinterpret_cast<const float4*>(x_j);
    int ntile = (pend - pstart + 15) >> 4;

    auto fetch = [&](int ti, uint4& rec, float4& fa, float4& fb, int& pdv) {
        int p = pstart + ti * 16 + row16;
        bool v = p < pend;
        int pp = v ? p : pstart;
        rec = cellrec[pp];
        int src = rec.x;
        fa = x4[src * 8 + 2 * hi];
        fb = x4[src * 8 + 2 * hi + 1];
        pdv = v ? (int)rec.y : -1;
    };

    int it = wid;
    uint4 rec; float4 fa, fb; int pdv;
    if (it < ntile) fetch(it, rec, fa, fb, pdv);

    for (; it < ntile; it += 4) {
        uint4 recN; float4 faN, fbN; int pdvN = -1;
        bool hn = (it + 4) < ntile;
        if (hn) fetch(it + 4, recN, faN, fbN, pdvN);   // loads fly under compute

        float tx = __uint_as_float(rec.z), ty = __uint_as_float(rec.w);
        float fx = tx - (float)kx0, fy = ty - (float)ky0;
        float bx0 = 1.f - fx, by0 = 1.f - fy;
        float bc[4] = { bx0 * by0, bx0 * fy, fx * by0, fx * fy };
        float fl[8] = { fa.x, fa.y, fa.z, fa.w, fb.x, fb.y, fb.z, fb.w };

        f32x4 a0 = {0,0,0,0}, a1 = {0,0,0,0};
        #pragma unroll
        for (int kk = 0; kk < 4; ++kk) {
            float s = bc[kk];
            uint4v u;
            u[0] = pk2(fl[0] * s, fl[1] * s);
            u[1] = pk2(fl[2] * s, fl[3] * s);
            u[2] = pk2(fl[4] * s, fl[5] * s);
            u[3] = pk2(fl[6] * s, fl[7] * s);
            short8 av = __builtin_bit_cast(short8, u);
            a0 = __builtin_amdgcn_mfma_f32_16x16x32_bf16(av, w0[kk], a0, 0, 0, 0);
            a1 = __builtin_amdgcn_mfma_f32_16x16x32_bf16(av, w1[kk], a1, 0, 0, 0);
        }
        // C row r = edge 4*hi+r ; col = row16 (+16). Plain stores to msg row.
        #pragma unroll
        for (int r = 0; r < 4; ++r) {
            int pd = __shfl(pdv, 4 * hi + r, 64);
            if (pd >= 0) {
                float* mrow = msg + (size_t)pd * 32;
                mrow[row16]      = a0[r];
                mrow[row16 + 16] = a1[r];
            }
        }
        rec = recN; fa = faN; fb = fbN; pdv = pdvN;
    }
}

// -------- Phase B: per-bin streaming reduce, float4 + 4-deep MLP ------------
// thread (rr=t>>3, j=t&7): row-slot rr reads 16B chunk j of msg row.
// 4-deep unroll: rows i, i+32, i+64, i+96 all in flight before atomics.
__global__ __launch_bounds__(256, 4) void bconv_reduce(
    const float* __restrict__ msg, const unsigned char* __restrict__ dloc8,
    const int* __restrict__ binbase, float* __restrict__ out, int N)
{
    __shared__ float acc[BINSZ][33];
    int t = threadIdx.x, bin = blockIdx.x;
    for (int i = t; i < BINSZ * 33; i += 256) (&acc[0][0])[i] = 0.f;
    __syncthreads();

    int s0 = binbase[bin], s1 = binbase[bin + 1];
    int rr = t >> 3;            // 32 row slots
    int j  = t & 7;             // float4 chunk within row
    int jc = j * 4;
    const float4* m4 = reinterpret_cast<const float4*>(msg);

    int i = s0 + rr;
    for (; i + 96 < s1; i += 128) {
        float4 v0 = m4[(size_t)(i)      * 8 + j];
        float4 v1 = m4[(size_t)(i + 32) * 8 + j];
        float4 v2 = m4[(size_t)(i + 64) * 8 + j];
        float4 v3 = m4[(size_t)(i + 96) * 8 + j];
        int d0 = dloc8[i], d1 = dloc8[i + 32], d2 = dloc8[i + 64], d3 = dloc8[i + 96];
        atomicAdd(&acc[d0][jc + 0], v0.x); atomicAdd(&acc[d0][jc + 1], v0.y);
        atomicAdd(&acc[d0][jc + 2], v0.z); atomicAdd(&acc[d0][jc + 3], v0.w);
        atomicAdd(&acc[d1][jc + 0], v1.x); atomicAdd(&acc[d1][jc + 1], v1.y);
        atomicAdd(&acc[d1][jc + 2], v1.z); atomicAdd(&acc[d1][jc + 3], v1.w);
        atomicAdd(&acc[d2][jc + 0], v2.x); atomicAdd(&acc[d2][jc + 1], v2.y);
        atomicAdd(&acc[d2][jc + 2], v2.z); atomicAdd(&acc[d2][jc + 3], v2.w);
        atomicAdd(&acc[d3][jc + 0], v3.x); atomicAdd(&acc[d3][jc + 1], v3.y);
        atomicAdd(&acc[d3][jc + 2], v3.z); atomicAdd(&acc[d3][jc + 3], v3.w);
    }
    for (; i < s1; i += 32) {
        float4 v = m4[(size_t)i * 8 + j];
        int d = dloc8[i];
        atomicAdd(&acc[d][jc + 0], v.x); atomicAdd(&acc[d][jc + 1], v.y);
        atomicAdd(&acc[d][jc + 2], v.z); atomicAdd(&acc[d][jc + 3], v.w);
    }
    __syncthreads();

    int nloc = t >> 3;
    int node = bin * BINSZ + nloc;
    if (node < N) {
        float4 v;
        v.x = acc[nloc][jc];     v.y = acc[nloc][jc + 1];
        v.z = acc[nloc][jc + 2]; v.w = acc[nloc][jc + 3];
        *reinterpret_cast<float4*>(&out[(size_t)node * F + jc]) = v;
    }
}

// ====================== FALLBACK 1 (R3 path): cell sort + global atomics ====
__global__ __launch_bounds__(256) void hist_kernel(
    const float* __restrict__ attr, int E, int* __restrict__ counts)
{
    __shared__ int hh[9];
    int b = blockIdx.x, t = threadIdx.x;
    if (t < 9) hh[t] = 0;
    __syncthreads();
    int start = b * OSCH, end = min(start + OSCH, E);
    for (int e = start + t; e < end; e += 256) {
        float2 a = reinterpret_cast<const float2*>(attr)[e];
        float tx = fminf(fmaxf((a.x + 1.0f) * 1.5f, 0.f), 3.f);
        float ty = fminf(fmaxf((a.y + 1.0f) * 1.5f, 0.f), 3.f);
        atomicAdd(&hh[min((int)tx, 2) * 3 + min((int)ty, 2)], 1);
    }
    __syncthreads();
    if (t < 9) counts[b * 9 + t] = hh[t];
}

__global__ __launch_bounds__(512) void scan_kernel(
    int* __restrict__ ws, int* __restrict__ counts, int nblk)
{
    __shared__ int s[OMAXNBLK * 9];
    __shared__ int tot[9];
    __shared__ int coff[9];
    int n = nblk * 9;
    for (int i = threadIdx.x; i < n; i += 512) s[i] = counts[i];
    __syncthreads();
    if (threadIdx.x < 9) {
        int c = threadIdx.x, run = 0;
        for (int b = 0; b < nblk; ++b) {
            int v = s[b * 9 + c];
            s[b * 9 + c] = run;
            run += v;
        }
        tot[c] = run;
    }
    __syncthreads();
    if (threadIdx.x == 0) {
        int off = 0, boff = 0;
        for (int c = 0; c < 9; ++c) {
            ws[c] = off;  coff[c] = off;
            ws[16 + c] = boff;
            off  += tot[c];
            boff += (tot[c] + EPB - 1) / EPB;
        }
        ws[9] = off;
        ws[16 + 9] = boff;
    }
    __syncthreads();
    for (int i = threadIdx.x; i < n; i += 512)
        counts[i] = s[i] + coff[i % 9];
}

__global__ __launch_bounds__(256) void scatter_kernel(
    const float* __restrict__ attr, int E,
    const int* __restrict__ bases, int* __restrict__ sorted)
{
    __shared__ int cur[9];
    int b = blockIdx.x, t = threadIdx.x;
    if (t < 9) cur[t] = bases[b * 9 + t];
    __syncthreads();
    int start = b * OSCH, end = min(start + OSCH, E);
    for (int e = start + t; e < end; e += 256) {
        float2 a = reinterpret_cast<const float2*>(attr)[e];
        float tx = fminf(fmaxf((a.x + 1.0f) * 1.5f, 0.f), 3.f);
        float ty = fminf(fmaxf((a.y + 1.0f) * 1.5f, 0.f), 3.f);
        int c = min((int)tx, 2) * 3 + min((int)ty, 2);
        int pos = atomicAdd(&cur[c], 1);
        sorted[pos] = e;
    }
}

__global__ __launch_bounds__(256) void bconv_mfma(
    const float* __restrict__ x_j, const int* __restrict__ ei,
    const float* __restrict__ attr, const float* __restrict__ weight,
    const int* __restrict__ ws, const int* __restrict__ sorted,
    float* __restrict__ out, int E)
{
    int b = blockIdx.x;
    const int* blkoff = ws + 16;
    if (b >= blkoff[9]) return;
    int c = 0;
    #pragma unroll
    for (int q = 1; q < 9; ++q) c += (b >= blkoff[q]) ? 1 : 0;
    int kx0 = c / 3, ky0 = c - 3 * (c / 3);
    int local  = b - blkoff[c];
    int cstart = ws[c], cend = ws[c + 1];
    int pstart = cstart + local * EPB;
    int pend   = min(pstart + EPB, cend);

    int t = threadIdx.x;
    int wid = t >> 6, lane = t & 63;
    int row16 = lane & 15, hi = lane >> 4;

    short8 wb[4][2];
    #pragma unroll
    for (int kk = 0; kk < 4; ++kk) {
        int ks = (kx0 + (kk >> 1)) * NB + (ky0 + (kk & 1));
        const float* wp = weight + (size_t)ks * F * F;
        #pragma unroll
        for (int n = 0; n < 2; ++n) {
            short8 v;
            #pragma unroll
            for (int j = 0; j < 8; ++j)
                v[j] = f2bf(wp[(8 * hi + j) * F + row16 + 16 * n]);
            wb[kk][n] = v;
        }
    }

    int wstart = pstart + wid * (EPB / 4);
    int wend   = min(wstart + (EPB / 4), pend);
    if (wstart >= wend) return;

    int ntiles = (wend - wstart + 15) >> 4;
    for (int tt = 0; tt < ntiles; ++tt) {
        int p = wstart + tt * 16 + row16;
        bool v = p < wend;
        int pp = v ? p : wstart;
        int e  = sorted[pp];
        int dst = ei[e];
        int srcn = ei[E + e];
        float2 a = reinterpret_cast<const float2*>(attr)[e];
        const float4* xr = reinterpret_cast<const float4*>(x_j + (size_t)srcn * F);
        float4 fa = xr[2 * hi];
        float4 fb = xr[2 * hi + 1];

        float fx = (a.x + 1.0f) * 1.5f - (float)kx0;
        float fy = (a.y + 1.0f) * 1.5f - (float)ky0;
        float vs = v ? 1.f : 0.f;
        float bx0 = (1.f - fx) * vs, bx1 = fx * vs;
        float bc[4] = { bx0 * (1.f - fy), bx0 * fy, bx1 * (1.f - fy), bx1 * fy };

        f32x4 a0 = {0,0,0,0}, a1 = {0,0,0,0};
        #pragma unroll
        for (int kk = 0; kk < 4; ++kk) {
            float s = bc[kk];
            uint4v u;
            u[0] = pk2(fa.x * s, fa.y * s);
            u[1] = pk2(fa.z * s, fa.w * s);
            u[2] = pk2(fb.x * s, fb.y * s);
            u[3] = pk2(fb.z * s, fb.w * s);
            short8 av = __builtin_bit_cast(short8, u);
            a0 = __builtin_amdgcn_mfma_f32_16x16x32_bf16(av, wb[kk][0], a0, 0, 0, 0);
            a1 = __builtin_amdgcn_mfma_f32_16x16x32_bf16(av, wb[kk][1], a1, 0, 0, 0);
        }
        #pragma unroll
        for (int r = 0; r < 4; ++r) {
            int d = __shfl(v ? dst : -1, 4 * hi + r, 64);
            if (d >= 0) {
                atomicAdd(&out[(size_t)d * F + row16],      a0[r]);
                atomicAdd(&out[(size_t)d * F + 16 + row16], a1[r]);
            }
        }
    }
}

// ====================== FALLBACK 2: f32 VALU path ===========================
__global__ __launch_bounds__(256) void bconv_fallback(
    const float* __restrict__ x_j, const int* __restrict__ ei,
    const float* __restrict__ attr, const float* __restrict__ weight,
    float* __restrict__ out, int E)
{
    __shared__ float wl[16 * F * F];
    __shared__ float featl[8][F];
    for (int idx = threadIdx.x; idx < 4096; idx += 256)
        reinterpret_cast<float4*>(wl)[idx] = reinterpret_cast<const float4*>(weight)[idx];
    __syncthreads();

    int lane = threadIdx.x & 31, eslot = threadIdx.x >> 5;
    for (int p = blockIdx.x * 8 + eslot; p < E; p += gridDim.x * 8) {
        int dst = ei[p], srcn = ei[E + p];
        float ax = attr[2 * p], ay = attr[2 * p + 1];
        featl[eslot][lane] = x_j[(size_t)srcn * F + lane];
        float tx = (ax + 1.0f) * 1.5f, ty = (ay + 1.0f) * 1.5f;
        int kx0 = min(max((int)tx, 0), 2), ky0 = min(max((int)ty, 0), 2);
        float fx = tx - kx0, fy = ty - ky0;
        float bcv[4] = { (1.0f - fx) * (1.0f - fy), (1.0f - fx) * fy,
                         fx * (1.0f - fy), fx * fy };
        float msg = 0.f;
        const float4* f4 = reinterpret_cast<const float4*>(&featl[eslot][0]);
        #pragma unroll
        for (int kk = 0; kk < 4; ++kk) {
            int k = (kx0 + (kk >> 1)) * NB + (ky0 + (kk & 1));
            const float* wk = wl + k * F * F;
            float a2 = 0.f;
            #pragma unroll
            for (int j = 0; j < 8; ++j) {
                float4 f = f4[j];
                a2 = fmaf(f.x, wk[(4 * j + 0) * F + lane], a2);
                a2 = fmaf(f.y, wk[(4 * j + 1) * F + lane], a2);
                a2 = fmaf(f.z, wk[(4 * j + 2) * F + lane], a2);
                a2 = fmaf(f.w, wk[(4 * j + 3) * F + lane], a2);
            }
            msg = fmaf(bcv[kk], a2, msg);
        }
        atomicAdd(&out[(size_t)dst * F + lane], msg);
    }
}

extern "C" void kernel_launch(void* const* d_in, const int* in_sizes, int n_in,
                              void* d_out, int out_size, void* d_ws, size_t ws_size,
                              hipStream_t stream) {
    const float* x_j    = (const float*)d_in[1];
    const int*   ei     = (const int*)d_in[2];
    const float* attr   = (const float*)d_in[3];
    const float* weight = (const float*)d_in[4];
    float* out = (float*)d_out;
    int E = in_sizes[2] / 2;
    int N = in_sizes[0] / F;

    int nbin = (N + BINSZ - 1) >> BINSH;

    // --- new-path ws layout (ints) ---
    int o_bincnt   = 0;                       // nbin
    int o_cellcnt  = o_bincnt + nbin;         // 9   (memset covers bincnt+cellcnt)
    int o_binbase  = o_cellcnt + 9;           // nbin+1
    int o_bincur   = o_binbase + nbin + 1;    // nbin
    int o_cellbase = o_bincur + nbin;         // 10
    int o_cellcur  = o_cellbase + 10;         // 9
    int o_blkoff   = o_cellcur + 9;           // 10
    int o_wbf      = (o_blkoff + 10 + 3) & ~3;          // 8192 ints
    int o_dloc     = o_wbf + 8192;                      // ceil(E/4) ints
    int o_cellrec  = (o_dloc + (E + 3) / 4 + 3) & ~3;   // 4E ints (uint4)
    size_t o_msg   = (size_t)((o_cellrec + 4 * (size_t)E + 3) & ~3);
    size_t need_new = (o_msg + 32 * (size_t)E) * sizeof(int);

    // --- old-path ws layout ---
    int nblk_sort = (E + OSCH - 1) / OSCH;
    int sorted_off = 32 + ((nblk_sort * 9 + 15) & ~15);
    size_t need_old = (size_t)(sorted_off + E) * sizeof(int);

    if (nbin <= MAXBIN && N <= 65536 && E < (1 << 24) && ws_size >= need_new) {
        int* ws = (int*)d_ws;
        short* wbf = (short*)(ws + o_wbf);
        unsigned char* dloc8 = (unsigned char*)(ws + o_dloc);
        uint4* cellrec = (uint4*)(ws + o_cellrec);
        float* msg = (float*)(ws + o_msg);

        hipMemsetAsync(ws, 0, (size_t)(nbin + 9) * sizeof(int), stream);
        w_prep<<<64, 256, 0, stream>>>(weight, wbf);
        h2_kernel<<<256, 256, 0, stream>>>(ei, attr, E, nbin,
                                           ws + o_bincnt, ws + o_cellcnt);
        scan2_kernel<<<1, 256, 0, stream>>>(ws + o_bincnt, ws + o_binbase,
                                            ws + o_bincur, ws + o_cellcnt,
                                            ws + o_cellbase, ws + o_cellcur,
                                            ws + o_blkoff, nbin);
        scat2_kernel<<<(E + SCH - 1) / SCH, 256, 0, stream>>>(
            ei, attr, E, nbin, ws + o_bincur, ws + o_cellcur, cellrec, dloc8);
        int nblkA = (E + EPB - 1) / EPB + 9;
        bconv_msg<<<nblkA, 256, 0, stream>>>(x_j, wbf, ws + o_cellbase,
                                             ws + o_blkoff, cellrec, msg);
        bconv_reduce<<<nbin, 256, 0, stream>>>(msg, dloc8, ws + o_binbase, out, N);
    } else if (nblk_sort <= OMAXNBLK && ws_size >= need_old) {
        hipMemsetAsync(d_out, 0, (size_t)out_size * sizeof(float), stream);
        int* ws      = (int*)d_ws;
        int* counts  = ws + 32;
        int* sorted  = ws + sorted_off;
        hist_kernel<<<nblk_sort, 256, 0, stream>>>(attr, E, counts);
        scan_kernel<<<1, 512, 0, stream>>>(ws, counts, nblk_sort);
        scatter_kernel<<<nblk_sort, 256, 0, stream>>>(attr, E, counts, sorted);
        int nblk_main = (E + EPB - 1) / EPB + 9;
        bconv_mfma<<<nblk_main, 256, 0, stream>>>(x_j, ei, attr, weight, ws, sorted, out, E);
    } else {
        hipMemsetAsync(d_out, 0, (size_t)out_size * sizeof(float), stream);
        bconv_fallback<<<2048, 256, 0, stream>>>(x_j, ei, attr, weight, out, E);
    }
}

// Round 9
// 110.960 us; speedup vs baseline: 2.1693x; 2.1565x over previous
//
#include <hip/hip_runtime.h>
#include <hip/hip_bf16.h>

typedef short short8 __attribute__((ext_vector_type(8)));
typedef float f32x4 __attribute__((ext_vector_type(4)));
typedef unsigned uint4v __attribute__((ext_vector_type(4)));

#define F 32
#define NB 4
#define BINSH 5        // 32 nodes per dst-bin
#define BINSZ 32
#define EPB 512        // edges per Phase-A block
#define SCH 4096       // edges per scatter block
#define MAXBIN 2048
#define CAPB 2048      // reduce: rows permuted per chunk
// old path constants
#define OSCH 2048
#define OMAXNBLK 1024

__device__ __forceinline__ short f2bf(float f) {   // RNE f32->bf16
    unsigned u = __float_as_uint(f);
    unsigned r = (u + 0x7FFFu + ((u >> 16) & 1u)) >> 16;
    return (short)r;
}

__device__ __forceinline__ unsigned pk2(float a, float b) {  // packed bf16 pair
    __hip_bfloat162 h = __float22bfloat162_rn(make_float2(a, b));
    union { __hip_bfloat162 h; unsigned u; } cv; cv.h = h; return cv.u;
}

// -------- weight prep: bf16 B-fragment layout into ws (32 KB, L2-resident) --
__global__ __launch_bounds__(256) void w_prep(
    const float* __restrict__ w, short* __restrict__ wbf)
{
    int idx = blockIdx.x * 256 + threadIdx.x;   // 64 x 256 = 16384
    int k = idx >> 10, rem = idx & 1023, i = rem >> 5, o = rem & 31;
    int slot = (((k * 4 + (i >> 3)) * 2 + (o >> 4)) * 16 + (o & 15)) * 8 + (i & 7);
    wbf[slot] = f2bf(w[idx]);
}

// -------- combined hist: dst-bin (LDS) + cell (LDS), flush to global --------
__global__ __launch_bounds__(256) void h2_kernel(
    const int* __restrict__ ei, const float* __restrict__ attr, int E, int nbin,
    int* __restrict__ bincnt, int* __restrict__ cellcnt)
{
    __shared__ int hb[MAXBIN];
    __shared__ int hc[9];
    int t = threadIdx.x;
    for (int i = t; i < nbin; i += 256) hb[i] = 0;
    if (t < 9) hc[t] = 0;
    __syncthreads();
    int stride = gridDim.x * blockDim.x;
    for (int e = blockIdx.x * blockDim.x + t; e < E; e += stride) {
        int dst = ei[e];
        float2 a = reinterpret_cast<const float2*>(attr)[e];
        float tx = fminf(fmaxf((a.x + 1.0f) * 1.5f, 0.f), 3.f);
        float ty = fminf(fmaxf((a.y + 1.0f) * 1.5f, 0.f), 3.f);
        int kx = min((int)tx, 2), ky = min((int)ty, 2);
        atomicAdd(&hb[dst >> BINSH], 1);
        atomicAdd(&hc[kx * 3 + ky], 1);
    }
    __syncthreads();
    for (int i = t; i < nbin; i += 256)
        if (hb[i]) atomicAdd(&bincnt[i], hb[i]);
    if (t < 9 && hc[t]) atomicAdd(&cellcnt[t], hc[t]);
}

// -------- scan: bins -> binbase/bincur ; cells -> cellbase/cellcur/blkoff ---
__global__ __launch_bounds__(256) void scan2_kernel(
    const int* __restrict__ bincnt, int* __restrict__ binbase,
    int* __restrict__ bincur, const int* __restrict__ cellcnt,
    int* __restrict__ cellbase, int* __restrict__ cellcur,
    int* __restrict__ blkoff, int nbin)
{
    __shared__ int part[256];
    int t = threadIdx.x;
    int chunk = (nbin + 255) / 256;
    int lo = t * chunk, hi = min(lo + chunk, nbin);
    int s = 0;
    for (int q = lo; q < hi; ++q) s += bincnt[q];
    part[t] = s;
    __syncthreads();
    if (t == 0) {
        int run = 0;
        for (int j = 0; j < 256; ++j) { int v = part[j]; part[j] = run; run += v; }
        binbase[nbin] = run;
    }
    __syncthreads();
    int run = part[t];
    for (int q = lo; q < hi; ++q) {
        binbase[q] = run; bincur[q] = run;
        run += bincnt[q];
    }
    if (t == 0) {
        int off = 0, boff = 0;
        for (int c = 0; c < 9; ++c) {
            cellbase[c] = off; cellcur[c] = off; blkoff[c] = boff;
            off  += cellcnt[c];
            boff += (cellcnt[c] + EPB - 1) / EPB;
        }
        cellbase[9] = off; blkoff[9] = boff;
    }
}

// -------- scatter: both orderings in one pass -------------------------------
// cellrec[poscell] = {src, posdst, tx_f32, ty_f32}; dloc8[posdst] = dst&31
__global__ __launch_bounds__(256) void scat2_kernel(
    const int* __restrict__ ei, const float* __restrict__ attr, int E, int nbin,
    int* __restrict__ bincur, int* __restrict__ cellcur,
    uint4* __restrict__ cellrec, unsigned char* __restrict__ dloc8)
{
    __shared__ int hb[MAXBIN];
    __shared__ int hc[9];
    int t = threadIdx.x, b = blockIdx.x;
    int start = b * SCH, end = min(start + SCH, E);
    for (int i = t; i < nbin; i += 256) hb[i] = 0;
    if (t < 9) hc[t] = 0;
    __syncthreads();
    for (int e = start + t; e < end; e += 256) {
        int dst = ei[e];
        float2 a = reinterpret_cast<const float2*>(attr)[e];
        float tx = fminf(fmaxf((a.x + 1.0f) * 1.5f, 0.f), 3.f);
        float ty = fminf(fmaxf((a.y + 1.0f) * 1.5f, 0.f), 3.f);
        int kx = min((int)tx, 2), ky = min((int)ty, 2);
        atomicAdd(&hb[dst >> BINSH], 1);
        atomicAdd(&hc[kx * 3 + ky], 1);
    }
    __syncthreads();
    for (int k = t; k < nbin; k += 256) {
        int c = hb[k];
        if (c) hb[k] = atomicAdd(&bincur[k], c);
    }
    if (t < 9) hc[t] = atomicAdd(&cellcur[t], hc[t]);
    __syncthreads();
    for (int e = start + t; e < end; e += 256) {
        int dst = ei[e];
        int src = ei[E + e];
        float2 a = reinterpret_cast<const float2*>(attr)[e];
        float tx = fminf(fmaxf((a.x + 1.0f) * 1.5f, 0.f), 3.f);
        float ty = fminf(fmaxf((a.y + 1.0f) * 1.5f, 0.f), 3.f);
        int kx = min((int)tx, 2), ky = min((int)ty, 2);
        int pd = atomicAdd(&hb[dst >> BINSH], 1);
        int pc = atomicAdd(&hc[kx * 3 + ky], 1);
        uint4 rec;
        rec.x = (unsigned)src;
        rec.y = (unsigned)pd;
        rec.z = __float_as_uint(tx);
        rec.w = __float_as_uint(ty);
        cellrec[pc] = rec;
        dloc8[pd] = (unsigned char)(dst & (BINSZ - 1));
    }
}

// -------- Phase A: cell-sorted tiles -> per-edge messages (plain stores) ----
__global__ __launch_bounds__(256, 4) void bconv_msg(
    const float* __restrict__ x_j, const short* __restrict__ wbf,
    const int* __restrict__ cellbase, const int* __restrict__ blkoff,
    const uint4* __restrict__ cellrec, float* __restrict__ msg)
{
    int b = blockIdx.x;
    if (b >= blkoff[9]) return;
    int c = 0;
    #pragma unroll
    for (int q = 1; q < 9; ++q) c += (b >= blkoff[q]) ? 1 : 0;
    int kx0 = c / 3, ky0 = c - 3 * (c / 3);
    int local  = b - blkoff[c];
    int cstart = cellbase[c], cend = cellbase[c + 1];
    int pstart = cstart + local * EPB;
    int pend   = min(pstart + EPB, cend);
    if (pstart >= pend) return;

    int t = threadIdx.x;
    int wid = t >> 6, lane = t & 63;
    int row16 = lane & 15, hi = lane >> 4;

    // B fragments for this cell (8 x 16B loads from L2-resident wbf)
    short8 w0[4], w1[4];
    #pragma unroll
    for (int kk = 0; kk < 4; ++kk) {
        int ks = (kx0 + (kk >> 1)) * NB + (ky0 + (kk & 1));
        w0[kk] = *reinterpret_cast<const short8*>(
            wbf + (((ks * 4 + hi) * 2 + 0) * 16 + row16) * 8);
        w1[kk] = *reinterpret_cast<const short8*>(
            wbf + (((ks * 4 + hi) * 2 + 1) * 16 + row16) * 8);
    }

    const float4* x4 = reinterpret_cast<const float4*>(x_j);
    int ntile = (pend - pstart + 15) >> 4;

    auto fetch = [&](int ti, uint4& rec, float4& fa, float4& fb, int& pdv) {
        int p = pstart + ti * 16 + row16;
        bool v = p < pend;
        int pp = v ? p : pstart;
        rec = cellrec[pp];
        int src = rec.x;
        fa = x4[src * 8 + 2 * hi];
        fb = x4[src * 8 + 2 * hi + 1];
        pdv = v ? (int)rec.y : -1;
    };

    int it = wid;
    uint4 rec; float4 fa, fb; int pdv;
    if (it < ntile) fetch(it, rec, fa, fb, pdv);

    for (; it < ntile; it += 4) {
        uint4 recN; float4 faN, fbN; int pdvN = -1;
        bool hn = (it + 4) < ntile;
        if (hn) fetch(it + 4, recN, faN, fbN, pdvN);   // loads fly under compute

        float tx = __uint_as_float(rec.z), ty = __uint_as_float(rec.w);
        float fx = tx - (float)kx0, fy = ty - (float)ky0;
        float bx0 = 1.f - fx, by0 = 1.f - fy;
        float bc[4] = { bx0 * by0, bx0 * fy, fx * by0, fx * fy };
        float fl[8] = { fa.x, fa.y, fa.z, fa.w, fb.x, fb.y, fb.z, fb.w };

        f32x4 a0 = {0,0,0,0}, a1 = {0,0,0,0};
        #pragma unroll
        for (int kk = 0; kk < 4; ++kk) {
            float s = bc[kk];
            uint4v u;
            u[0] = pk2(fl[0] * s, fl[1] * s);
            u[1] = pk2(fl[2] * s, fl[3] * s);
            u[2] = pk2(fl[4] * s, fl[5] * s);
            u[3] = pk2(fl[6] * s, fl[7] * s);
            short8 av = __builtin_bit_cast(short8, u);
            a0 = __builtin_amdgcn_mfma_f32_16x16x32_bf16(av, w0[kk], a0, 0, 0, 0);
            a1 = __builtin_amdgcn_mfma_f32_16x16x32_bf16(av, w1[kk], a1, 0, 0, 0);
        }
        // C row r = edge 4*hi+r ; col = row16 (+16). Plain stores to msg row.
        #pragma unroll
        for (int r = 0; r < 4; ++r) {
            int pd = __shfl(pdv, 4 * hi + r, 64);
            if (pd >= 0) {
                float* mrow = msg + (size_t)pd * 32;
                mrow[row16]      = a0[r];
                mrow[row16 + 16] = a1[r];
            }
        }
        rec = recN; fa = faN; fb = fbN; pdv = pdvN;
    }
}

// -------- Phase B: per-node register accumulation (NO LDS atomics on data) --
// Block = bin. Build per-node permutation of the bin's rows (2 LDS atomics/row),
// then 8-thread group g sums node g's rows in registers; one coalesced store.
__global__ __launch_bounds__(256, 8) void bconv_reduce(
    const float* __restrict__ msg, const unsigned char* __restrict__ dloc8,
    const int* __restrict__ binbase, float* __restrict__ out, int N)
{
    __shared__ unsigned short perm[CAPB];
    __shared__ int cnt[32], cbase[33], cur[32];

    int t = threadIdx.x, bin = blockIdx.x;
    int g = t >> 3, j = t & 7, jc = j * 4;
    int s0 = binbase[bin], s1 = binbase[bin + 1];
    const float4* m4 = reinterpret_cast<const float4*>(msg);

    float4 accv = {0.f, 0.f, 0.f, 0.f};

    for (int chunk = s0; chunk < s1; chunk += CAPB) {
        int clen = min(CAPB, s1 - chunk);
        if (t < 32) cnt[t] = 0;
        __syncthreads();
        for (int i = t; i < clen; i += 256)
            atomicAdd(&cnt[dloc8[chunk + i]], 1);
        __syncthreads();
        if (t == 0) {
            int run = 0;
            #pragma unroll
            for (int c2 = 0; c2 < 32; ++c2) { cbase[c2] = run; run += cnt[c2]; }
            cbase[32] = run;
        }
        __syncthreads();
        if (t < 32) cur[t] = cbase[t];
        __syncthreads();
        for (int i = t; i < clen; i += 256) {
            int d = dloc8[chunk + i];
            int r = atomicAdd(&cur[d], 1);
            perm[r] = (unsigned short)i;
        }
        __syncthreads();

        int lo = cbase[g], hi2 = cbase[g + 1];
        int k = lo;
        for (; k + 3 < hi2; k += 4) {           // 4 independent loads in flight
            int i0 = perm[k], i1 = perm[k + 1], i2 = perm[k + 2], i3 = perm[k + 3];
            float4 v0 = m4[(size_t)(chunk + i0) * 8 + j];
            float4 v1 = m4[(size_t)(chunk + i1) * 8 + j];
            float4 v2 = m4[(size_t)(chunk + i2) * 8 + j];
            float4 v3 = m4[(size_t)(chunk + i3) * 8 + j];
            accv.x += v0.x; accv.y += v0.y; accv.z += v0.z; accv.w += v0.w;
            accv.x += v1.x; accv.y += v1.y; accv.z += v1.z; accv.w += v1.w;
            accv.x += v2.x; accv.y += v2.y; accv.z += v2.z; accv.w += v2.w;
            accv.x += v3.x; accv.y += v3.y; accv.z += v3.z; accv.w += v3.w;
        }
        for (; k < hi2; ++k) {
            int i0 = perm[k];
            float4 v0 = m4[(size_t)(chunk + i0) * 8 + j];
            accv.x += v0.x; accv.y += v0.y; accv.z += v0.z; accv.w += v0.w;
        }
        __syncthreads();                        // perm reused next chunk
    }

    int node = bin * BINSZ + g;
    if (node < N)
        *reinterpret_cast<float4*>(&out[(size_t)node * F + jc]) = accv;
}

// ====================== FALLBACK 1 (R3 path): cell sort + global atomics ====
__global__ __launch_bounds__(256) void hist_kernel(
    const float* __restrict__ attr, int E, int* __restrict__ counts)
{
    __shared__ int hh[9];
    int b = blockIdx.x, t = threadIdx.x;
    if (t < 9) hh[t] = 0;
    __syncthreads();
    int start = b * OSCH, end = min(start + OSCH, E);
    for (int e = start + t; e < end; e += 256) {
        float2 a = reinterpret_cast<const float2*>(attr)[e];
        float tx = fminf(fmaxf((a.x + 1.0f) * 1.5f, 0.f), 3.f);
        float ty = fminf(fmaxf((a.y + 1.0f) * 1.5f, 0.f), 3.f);
        atomicAdd(&hh[min((int)tx, 2) * 3 + min((int)ty, 2)], 1);
    }
    __syncthreads();
    if (t < 9) counts[b * 9 + t] = hh[t];
}

__global__ __launch_bounds__(512) void scan_kernel(
    int* __restrict__ ws, int* __restrict__ counts, int nblk)
{
    __shared__ int s[OMAXNBLK * 9];
    __shared__ int tot[9];
    __shared__ int coff[9];
    int n = nblk * 9;
    for (int i = threadIdx.x; i < n; i += 512) s[i] = counts[i];
    __syncthreads();
    if (threadIdx.x < 9) {
        int c = threadIdx.x, run = 0;
        for (int b = 0; b < nblk; ++b) {
            int v = s[b * 9 + c];
            s[b * 9 + c] = run;
            run += v;
        }
        tot[c] = run;
    }
    __syncthreads();
    if (threadIdx.x == 0) {
        int off = 0, boff = 0;
        for (int c = 0; c < 9; ++c) {
            ws[c] = off;  coff[c] = off;
            ws[16 + c] = boff;
            off  += tot[c];
            boff += (tot[c] + EPB - 1) / EPB;
        }
        ws[9] = off;
        ws[16 + 9] = boff;
    }
    __syncthreads();
    for (int i = threadIdx.x; i < n; i += 512)
        counts[i] = s[i] + coff[i % 9];
}

__global__ __launch_bounds__(256) void scatter_kernel(
    const float* __restrict__ attr, int E,
    const int* __restrict__ bases, int* __restrict__ sorted)
{
    __shared__ int cur[9];
    int b = blockIdx.x, t = threadIdx.x;
    if (t < 9) cur[t] = bases[b * 9 + t];
    __syncthreads();
    int start = b * OSCH, end = min(start + OSCH, E);
    for (int e = start + t; e < end; e += 256) {
        float2 a = reinterpret_cast<const float2*>(attr)[e];
        float tx = fminf(fmaxf((a.x + 1.0f) * 1.5f, 0.f), 3.f);
        float ty = fminf(fmaxf((a.y + 1.0f) * 1.5f, 0.f), 3.f);
        int c = min((int)tx, 2) * 3 + min((int)ty, 2);
        int pos = atomicAdd(&cur[c], 1);
        sorted[pos] = e;
    }
}

__global__ __launch_bounds__(256) void bconv_mfma(
    const float* __restrict__ x_j, const int* __restrict__ ei,
    const float* __restrict__ attr, const float* __restrict__ weight,
    const int* __restrict__ ws, const int* __restrict__ sorted,
    float* __restrict__ out, int E)
{
    int b = blockIdx.x;
    const int* blkoff = ws + 16;
    if (b >= blkoff[9]) return;
    int c = 0;
    #pragma unroll
    for (int q = 1; q < 9; ++q) c += (b >= blkoff[q]) ? 1 : 0;
    int kx0 = c / 3, ky0 = c - 3 * (c / 3);
    int local  = b - blkoff[c];
    int cstart = ws[c], cend = ws[c + 1];
    int pstart = cstart + local * EPB;
    int pend   = min(pstart + EPB, cend);

    int t = threadIdx.x;
    int wid = t >> 6, lane = t & 63;
    int row16 = lane & 15, hi = lane >> 4;

    short8 wb[4][2];
    #pragma unroll
    for (int kk = 0; kk < 4; ++kk) {
        int ks = (kx0 + (kk >> 1)) * NB + (ky0 + (kk & 1));
        const float* wp = weight + (size_t)ks * F * F;
        #pragma unroll
        for (int n = 0; n < 2; ++n) {
            short8 v;
            #pragma unroll
            for (int j = 0; j < 8; ++j)
                v[j] = f2bf(wp[(8 * hi + j) * F + row16 + 16 * n]);
            wb[kk][n] = v;
        }
    }

    int wstart = pstart + wid * (EPB / 4);
    int wend   = min(wstart + (EPB / 4), pend);
    if (wstart >= wend) return;

    int ntiles = (wend - wstart + 15) >> 4;
    for (int tt = 0; tt < ntiles; ++tt) {
        int p = wstart + tt * 16 + row16;
        bool v = p < wend;
        int pp = v ? p : wstart;
        int e  = sorted[pp];
        int dst = ei[e];
        int srcn = ei[E + e];
        float2 a = reinterpret_cast<const float2*>(attr)[e];
        const float4* xr = reinterpret_cast<const float4*>(x_j + (size_t)srcn * F);
        float4 fa = xr[2 * hi];
        float4 fb = xr[2 * hi + 1];

        float fx = (a.x + 1.0f) * 1.5f - (float)kx0;
        float fy = (a.y + 1.0f) * 1.5f - (float)ky0;
        float vs = v ? 1.f : 0.f;
        float bx0 = (1.f - fx) * vs, bx1 = fx * vs;
        float bc[4] = { bx0 * (1.f - fy), bx0 * fy, bx1 * (1.f - fy), bx1 * fy };

        f32x4 a0 = {0,0,0,0}, a1 = {0,0,0,0};
        #pragma unroll
        for (int kk = 0; kk < 4; ++kk) {
            float s = bc[kk];
            uint4v u;
            u[0] = pk2(fa.x * s, fa.y * s);
            u[1] = pk2(fa.z * s, fa.w * s);
            u[2] = pk2(fb.x * s, fb.y * s);
            u[3] = pk2(fb.z * s, fb.w * s);
            short8 av = __builtin_bit_cast(short8, u);
            a0 = __builtin_amdgcn_mfma_f32_16x16x32_bf16(av, wb[kk][0], a0, 0, 0, 0);
            a1 = __builtin_amdgcn_mfma_f32_16x16x32_bf16(av, wb[kk][1], a1, 0, 0, 0);
        }
        #pragma unroll
        for (int r = 0; r < 4; ++r) {
            int d = __shfl(v ? dst : -1, 4 * hi + r, 64);
            if (d >= 0) {
                atomicAdd(&out[(size_t)d * F + row16],      a0[r]);
                atomicAdd(&out[(size_t)d * F + 16 + row16], a1[r]);
            }
        }
    }
}

// ====================== FALLBACK 2: f32 VALU path ===========================
__global__ __launch_bounds__(256) void bconv_fallback(
    const float* __restrict__ x_j, const int* __restrict__ ei,
    const float* __restrict__ attr, const float* __restrict__ weight,
    float* __restrict__ out, int E)
{
    __shared__ float wl[16 * F * F];
    __shared__ float featl[8][F];
    for (int idx = threadIdx.x; idx < 4096; idx += 256)
        reinterpret_cast<float4*>(wl)[idx] = reinterpret_cast<const float4*>(weight)[idx];
    __syncthreads();

    int lane = threadIdx.x & 31, eslot = threadIdx.x >> 5;
    for (int p = blockIdx.x * 8 + eslot; p < E; p += gridDim.x * 8) {
        int dst = ei[p], srcn = ei[E + p];
        float ax = attr[2 * p], ay = attr[2 * p + 1];
        featl[eslot][lane] = x_j[(size_t)srcn * F + lane];
        float tx = (ax + 1.0f) * 1.5f, ty = (ay + 1.0f) * 1.5f;
        int kx0 = min(max((int)tx, 0), 2), ky0 = min(max((int)ty, 0), 2);
        float fx = tx - kx0, fy = ty - ky0;
        float bcv[4] = { (1.0f - fx) * (1.0f - fy), (1.0f - fx) * fy,
                         fx * (1.0f - fy), fx * fy };
        float msg = 0.f;
        const float4* f4 = reinterpret_cast<const float4*>(&featl[eslot][0]);
        #pragma unroll
        for (int kk = 0; kk < 4; ++kk) {
            int k = (kx0 + (kk >> 1)) * NB + (ky0 + (kk & 1));
            const float* wk = wl + k * F * F;
            float a2 = 0.f;
            #pragma unroll
            for (int j = 0; j < 8; ++j) {
                float4 f = f4[j];
                a2 = fmaf(f.x, wk[(4 * j + 0) * F + lane], a2);
                a2 = fmaf(f.y, wk[(4 * j + 1) * F + lane], a2);
                a2 = fmaf(f.z, wk[(4 * j + 2) * F + lane], a2);
                a2 = fmaf(f.w, wk[(4 * j + 3) * F + lane], a2);
            }
            msg = fmaf(bcv[kk], a2, msg);
        }
        atomicAdd(&out[(size_t)dst * F + lane], msg);
    }
}

extern "C" void kernel_launch(void* const* d_in, const int* in_sizes, int n_in,
                              void* d_out, int out_size, void* d_ws, size_t ws_size,
                              hipStream_t stream) {
    const float* x_j    = (const float*)d_in[1];
    const int*   ei     = (const int*)d_in[2];
    const float* attr   = (const float*)d_in[3];
    const float* weight = (const float*)d_in[4];
    float* out = (float*)d_out;
    int E = in_sizes[2] / 2;
    int N = in_sizes[0] / F;

    int nbin = (N + BINSZ - 1) >> BINSH;

    // --- new-path ws layout (ints) ---
    int o_bincnt   = 0;                       // nbin
    int o_cellcnt  = o_bincnt + nbin;         // 9   (memset covers bincnt+cellcnt)
    int o_binbase  = o_cellcnt + 9;           // nbin+1
    int o_bincur   = o_binbase + nbin + 1;    // nbin
    int o_cellbase = o_bincur + nbin;         // 10
    int o_cellcur  = o_cellbase + 10;         // 9
    int o_blkoff   = o_cellcur + 9;           // 10
    int o_wbf      = (o_blkoff + 10 + 3) & ~3;          // 8192 ints
    int o_dloc     = o_wbf + 8192;                      // ceil(E/4) ints
    int o_cellrec  = (o_dloc + (E + 3) / 4 + 3) & ~3;   // 4E ints (uint4)
    size_t o_msg   = (size_t)((o_cellrec + 4 * (size_t)E + 3) & ~3);
    size_t need_new = (o_msg + 32 * (size_t)E) * sizeof(int);

    // --- old-path ws layout ---
    int nblk_sort = (E + OSCH - 1) / OSCH;
    int sorted_off = 32 + ((nblk_sort * 9 + 15) & ~15);
    size_t need_old = (size_t)(sorted_off + E) * sizeof(int);

    if (nbin <= MAXBIN && N <= 65536 && E < (1 << 24) && ws_size >= need_new) {
        int* ws = (int*)d_ws;
        short* wbf = (short*)(ws + o_wbf);
        unsigned char* dloc8 = (unsigned char*)(ws + o_dloc);
        uint4* cellrec = (uint4*)(ws + o_cellrec);
        float* msg = (float*)(ws + o_msg);

        hipMemsetAsync(ws, 0, (size_t)(nbin + 9) * sizeof(int), stream);
        w_prep<<<64, 256, 0, stream>>>(weight, wbf);
        h2_kernel<<<256, 256, 0, stream>>>(ei, attr, E, nbin,
                                           ws + o_bincnt, ws + o_cellcnt);
        scan2_kernel<<<1, 256, 0, stream>>>(ws + o_bincnt, ws + o_binbase,
                                            ws + o_bincur, ws + o_cellcnt,
                                            ws + o_cellbase, ws + o_cellcur,
                                            ws + o_blkoff, nbin);
        scat2_kernel<<<(E + SCH - 1) / SCH, 256, 0, stream>>>(
            ei, attr, E, nbin, ws + o_bincur, ws + o_cellcur, cellrec, dloc8);
        int nblkA = (E + EPB - 1) / EPB + 9;
        bconv_msg<<<nblkA, 256, 0, stream>>>(x_j, wbf, ws + o_cellbase,
                                             ws + o_blkoff, cellrec, msg);
        bconv_reduce<<<nbin, 256, 0, stream>>>(msg, dloc8, ws + o_binbase, out, N);
    } else if (nblk_sort <= OMAXNBLK && ws_size >= need_old) {
        hipMemsetAsync(d_out, 0, (size_t)out_size * sizeof(float), stream);
        int* ws      = (int*)d_ws;
        int* counts  = ws + 32;
        int* sorted  = ws + sorted_off;
        hist_kernel<<<nblk_sort, 256, 0, stream>>>(attr, E, counts);
        scan_kernel<<<1, 512, 0, stream>>>(ws, counts, nblk_sort);
        scatter_kernel<<<nblk_sort, 256, 0, stream>>>(attr, E, counts, sorted);
        int nblk_main = (E + EPB - 1) / EPB + 9;
        bconv_mfma<<<nblk_main, 256, 0, stream>>>(x_j, ei, attr, weight, ws, sorted, out, E);
    } else {
        hipMemsetAsync(d_out, 0, (size_t)out_size * sizeof(float), stream);
        bconv_fallback<<<2048, 256, 0, stream>>>(x_j, ei, attr, weight, out, E);
    }
}

// Round 10
// 98.696 us; speedup vs baseline: 2.4389x; 1.1243x over previous
//
#include <hip/hip_runtime.h>
#include <hip/hip_bf16.h>

typedef short short8 __attribute__((ext_vector_type(8)));
typedef float f32x4 __attribute__((ext_vector_type(4)));
typedef unsigned uint4v __attribute__((ext_vector_type(4)));

#define F 32
#define NB 4
#define BINSH 5        // 32 nodes per dst-bin
#define BINSZ 32
#define EPB 512        // edges per Phase-A block
#define SCH 4096       // edges per scatter block
#define MAXBIN 2048
#define CAPB 2048      // reduce: rows permuted per chunk
// old path constants
#define OSCH 2048
#define OMAXNBLK 1024

__device__ __forceinline__ short f2bf(float f) {   // RNE f32->bf16
    unsigned u = __float_as_uint(f);
    unsigned r = (u + 0x7FFFu + ((u >> 16) & 1u)) >> 16;
    return (short)r;
}

__device__ __forceinline__ unsigned pk2(float a, float b) {  // packed bf16 pair
    __hip_bfloat162 h = __float22bfloat162_rn(make_float2(a, b));
    union { __hip_bfloat162 h; unsigned u; } cv; cv.h = h; return cv.u;
}

// -------- weight prep: bf16 B-fragment layout into ws (32 KB, L2-resident) --
__global__ __launch_bounds__(256) void w_prep(
    const float* __restrict__ w, short* __restrict__ wbf)
{
    int idx = blockIdx.x * 256 + threadIdx.x;   // 64 x 256 = 16384
    int k = idx >> 10, rem = idx & 1023, i = rem >> 5, o = rem & 31;
    int slot = (((k * 4 + (i >> 3)) * 2 + (o >> 4)) * 16 + (o & 15)) * 8 + (i & 7);
    wbf[slot] = f2bf(w[idx]);
}

// -------- combined hist: dst-bin (LDS) + cell (LDS), flush to global --------
__global__ __launch_bounds__(256) void h2_kernel(
    const int* __restrict__ ei, const float* __restrict__ attr, int E, int nbin,
    int* __restrict__ bincnt, int* __restrict__ cellcnt)
{
    __shared__ int hb[MAXBIN];
    __shared__ int hc[9];
    int t = threadIdx.x;
    for (int i = t; i < nbin; i += 256) hb[i] = 0;
    if (t < 9) hc[t] = 0;
    __syncthreads();
    int stride = gridDim.x * blockDim.x;
    for (int e = blockIdx.x * blockDim.x + t; e < E; e += stride) {
        int dst = ei[e];
        float2 a = reinterpret_cast<const float2*>(attr)[e];
        float tx = fminf(fmaxf((a.x + 1.0f) * 1.5f, 0.f), 3.f);
        float ty = fminf(fmaxf((a.y + 1.0f) * 1.5f, 0.f), 3.f);
        int kx = min((int)tx, 2), ky = min((int)ty, 2);
        atomicAdd(&hb[dst >> BINSH], 1);
        atomicAdd(&hc[kx * 3 + ky], 1);
    }
    __syncthreads();
    for (int i = t; i < nbin; i += 256)
        if (hb[i]) atomicAdd(&bincnt[i], hb[i]);
    if (t < 9 && hc[t]) atomicAdd(&cellcnt[t], hc[t]);
}

// -------- scan: bins -> binbase/bincur ; cells -> cellbase/cellcur/blkoff ---
__global__ __launch_bounds__(256) void scan2_kernel(
    const int* __restrict__ bincnt, int* __restrict__ binbase,
    int* __restrict__ bincur, const int* __restrict__ cellcnt,
    int* __restrict__ cellbase, int* __restrict__ cellcur,
    int* __restrict__ blkoff, int nbin)
{
    __shared__ int part[256];
    int t = threadIdx.x;
    int chunk = (nbin + 255) / 256;
    int lo = t * chunk, hi = min(lo + chunk, nbin);
    int s = 0;
    for (int q = lo; q < hi; ++q) s += bincnt[q];
    part[t] = s;
    __syncthreads();
    if (t == 0) {
        int run = 0;
        for (int j = 0; j < 256; ++j) { int v = part[j]; part[j] = run; run += v; }
        binbase[nbin] = run;
    }
    __syncthreads();
    int run = part[t];
    for (int q = lo; q < hi; ++q) {
        binbase[q] = run; bincur[q] = run;
        run += bincnt[q];
    }
    if (t == 0) {
        int off = 0, boff = 0;
        for (int c = 0; c < 9; ++c) {
            cellbase[c] = off; cellcur[c] = off; blkoff[c] = boff;
            off  += cellcnt[c];
            boff += (cellcnt[c] + EPB - 1) / EPB;
        }
        cellbase[9] = off; blkoff[9] = boff;
    }
}

// -------- scatter: both orderings in one pass -------------------------------
// cellrec[poscell] = {src, posdst, tx_f32, ty_f32}; dloc8[posdst] = dst&31
__global__ __launch_bounds__(256) void scat2_kernel(
    const int* __restrict__ ei, const float* __restrict__ attr, int E, int nbin,
    int* __restrict__ bincur, int* __restrict__ cellcur,
    uint4* __restrict__ cellrec, unsigned char* __restrict__ dloc8)
{
    __shared__ int hb[MAXBIN];
    __shared__ int hc[9];
    int t = threadIdx.x, b = blockIdx.x;
    int start = b * SCH, end = min(start + SCH, E);
    for (int i = t; i < nbin; i += 256) hb[i] = 0;
    if (t < 9) hc[t] = 0;
    __syncthreads();
    for (int e = start + t; e < end; e += 256) {
        int dst = ei[e];
        float2 a = reinterpret_cast<const float2*>(attr)[e];
        float tx = fminf(fmaxf((a.x + 1.0f) * 1.5f, 0.f), 3.f);
        float ty = fminf(fmaxf((a.y + 1.0f) * 1.5f, 0.f), 3.f);
        int kx = min((int)tx, 2), ky = min((int)ty, 2);
        atomicAdd(&hb[dst >> BINSH], 1);
        atomicAdd(&hc[kx * 3 + ky], 1);
    }
    __syncthreads();
    for (int k = t; k < nbin; k += 256) {
        int c = hb[k];
        if (c) hb[k] = atomicAdd(&bincur[k], c);
    }
    if (t < 9) hc[t] = atomicAdd(&cellcur[t], hc[t]);
    __syncthreads();
    for (int e = start + t; e < end; e += 256) {
        int dst = ei[e];
        int src = ei[E + e];
        float2 a = reinterpret_cast<const float2*>(attr)[e];
        float tx = fminf(fmaxf((a.x + 1.0f) * 1.5f, 0.f), 3.f);
        float ty = fminf(fmaxf((a.y + 1.0f) * 1.5f, 0.f), 3.f);
        int kx = min((int)tx, 2), ky = min((int)ty, 2);
        int pd = atomicAdd(&hb[dst >> BINSH], 1);
        int pc = atomicAdd(&hc[kx * 3 + ky], 1);
        uint4 rec;
        rec.x = (unsigned)src;
        rec.y = (unsigned)pd;
        rec.z = __float_as_uint(tx);
        rec.w = __float_as_uint(ty);
        cellrec[pc] = rec;
        dloc8[pd] = (unsigned char)(dst & (BINSZ - 1));
    }
}

// -------- Phase A: cell-sorted tiles -> per-edge bf16 messages --------------
// msg row (64 B) = 16 u32 words; word w = pack(bf16 col w, bf16 col w+16).
__global__ __launch_bounds__(256, 4) void bconv_msg(
    const float* __restrict__ x_j, const short* __restrict__ wbf,
    const int* __restrict__ cellbase, const int* __restrict__ blkoff,
    const uint4* __restrict__ cellrec, unsigned* __restrict__ msg)
{
    int b = blockIdx.x;
    if (b >= blkoff[9]) return;
    int c = 0;
    #pragma unroll
    for (int q = 1; q < 9; ++q) c += (b >= blkoff[q]) ? 1 : 0;
    int kx0 = c / 3, ky0 = c - 3 * (c / 3);
    int local  = b - blkoff[c];
    int cstart = cellbase[c], cend = cellbase[c + 1];
    int pstart = cstart + local * EPB;
    int pend   = min(pstart + EPB, cend);
    if (pstart >= pend) return;

    int t = threadIdx.x;
    int wid = t >> 6, lane = t & 63;
    int row16 = lane & 15, hi = lane >> 4;

    // B fragments for this cell (8 x 16B loads from L2-resident wbf)
    short8 w0[4], w1[4];
    #pragma unroll
    for (int kk = 0; kk < 4; ++kk) {
        int ks = (kx0 + (kk >> 1)) * NB + (ky0 + (kk & 1));
        w0[kk] = *reinterpret_cast<const short8*>(
            wbf + (((ks * 4 + hi) * 2 + 0) * 16 + row16) * 8);
        w1[kk] = *reinterpret_cast<const short8*>(
            wbf + (((ks * 4 + hi) * 2 + 1) * 16 + row16) * 8);
    }

    const float4* x4 = reinterpret_cast<const float4*>(x_j);
    int ntile = (pend - pstart + 15) >> 4;

    auto fetch = [&](int ti, uint4& rec, float4& fa, float4& fb, int& pdv) {
        int p = pstart + ti * 16 + row16;
        bool v = p < pend;
        int pp = v ? p : pstart;
        rec = cellrec[pp];
        int src = rec.x;
        fa = x4[src * 8 + 2 * hi];
        fb = x4[src * 8 + 2 * hi + 1];
        pdv = v ? (int)rec.y : -1;
    };

    int it = wid;
    uint4 rec; float4 fa, fb; int pdv;
    if (it < ntile) fetch(it, rec, fa, fb, pdv);

    for (; it < ntile; it += 4) {
        uint4 recN; float4 faN, fbN; int pdvN = -1;
        bool hn = (it + 4) < ntile;
        if (hn) fetch(it + 4, recN, faN, fbN, pdvN);   // loads fly under compute

        float tx = __uint_as_float(rec.z), ty = __uint_as_float(rec.w);
        float fx = tx - (float)kx0, fy = ty - (float)ky0;
        float bx0 = 1.f - fx, by0 = 1.f - fy;
        float bc[4] = { bx0 * by0, bx0 * fy, fx * by0, fx * fy };
        float fl[8] = { fa.x, fa.y, fa.z, fa.w, fb.x, fb.y, fb.z, fb.w };

        f32x4 a0 = {0,0,0,0}, a1 = {0,0,0,0};
        #pragma unroll
        for (int kk = 0; kk < 4; ++kk) {
            float s = bc[kk];
            uint4v u;
            u[0] = pk2(fl[0] * s, fl[1] * s);
            u[1] = pk2(fl[2] * s, fl[3] * s);
            u[2] = pk2(fl[4] * s, fl[5] * s);
            u[3] = pk2(fl[6] * s, fl[7] * s);
            short8 av = __builtin_bit_cast(short8, u);
            a0 = __builtin_amdgcn_mfma_f32_16x16x32_bf16(av, w0[kk], a0, 0, 0, 0);
            a1 = __builtin_amdgcn_mfma_f32_16x16x32_bf16(av, w1[kk], a1, 0, 0, 0);
        }
        // C row r = edge 4*hi+r ; word row16 = (col row16, col row16+16).
        // One dword store per lane; 16 lanes = one 64-B segment per row.
        #pragma unroll
        for (int r = 0; r < 4; ++r) {
            int pd = __shfl(pdv, 4 * hi + r, 64);
            if (pd >= 0)
                msg[(size_t)pd * 16 + row16] = pk2(a0[r], a1[r]);
        }
        rec = recN; fa = faN; fb = fbN; pdv = pdvN;
    }
}

// -------- Phase B: per-node register accumulation over bf16 rows ------------
// 8-thread group g owns node g; thread j loads uint2 (words 2j,2j+1 = 8 B).
__global__ __launch_bounds__(256, 8) void bconv_reduce(
    const unsigned* __restrict__ msg, const unsigned char* __restrict__ dloc8,
    const int* __restrict__ binbase, float* __restrict__ out, int N)
{
    __shared__ unsigned short perm[CAPB];
    __shared__ int cnt[32], cbase[33], cur[32];

    int t = threadIdx.x, bin = blockIdx.x;
    int g = t >> 3, j = t & 7;
    int s0 = binbase[bin], s1 = binbase[bin + 1];
    const uint2* m2 = reinterpret_cast<const uint2*>(msg);

    float aAlo = 0.f, aAhi = 0.f, aBlo = 0.f, aBhi = 0.f;

    for (int chunk = s0; chunk < s1; chunk += CAPB) {
        int clen = min(CAPB, s1 - chunk);
        if (t < 32) cnt[t] = 0;
        __syncthreads();
        for (int i = t; i < clen; i += 256)
            atomicAdd(&cnt[dloc8[chunk + i]], 1);
        __syncthreads();
        if (t == 0) {
            int run = 0;
            #pragma unroll
            for (int c2 = 0; c2 < 32; ++c2) { cbase[c2] = run; run += cnt[c2]; }
            cbase[32] = run;
        }
        __syncthreads();
        if (t < 32) cur[t] = cbase[t];
        __syncthreads();
        for (int i = t; i < clen; i += 256) {
            int d = dloc8[chunk + i];
            int r = atomicAdd(&cur[d], 1);
            perm[r] = (unsigned short)i;
        }
        __syncthreads();

        int lo = cbase[g], hi2 = cbase[g + 1];
        int k = lo;
        for (; k + 3 < hi2; k += 4) {           // 4 independent loads in flight
            int i0 = perm[k], i1 = perm[k + 1], i2 = perm[k + 2], i3 = perm[k + 3];
            uint2 v0 = m2[(size_t)(chunk + i0) * 8 + j];
            uint2 v1 = m2[(size_t)(chunk + i1) * 8 + j];
            uint2 v2 = m2[(size_t)(chunk + i2) * 8 + j];
            uint2 v3 = m2[(size_t)(chunk + i3) * 8 + j];
            aAlo += __uint_as_float(v0.x << 16); aAhi += __uint_as_float(v0.x & 0xFFFF0000u);
            aBlo += __uint_as_float(v0.y << 16); aBhi += __uint_as_float(v0.y & 0xFFFF0000u);
            aAlo += __uint_as_float(v1.x << 16); aAhi += __uint_as_float(v1.x & 0xFFFF0000u);
            aBlo += __uint_as_float(v1.y << 16); aBhi += __uint_as_float(v1.y & 0xFFFF0000u);
            aAlo += __uint_as_float(v2.x << 16); aAhi += __uint_as_float(v2.x & 0xFFFF0000u);
            aBlo += __uint_as_float(v2.y << 16); aBhi += __uint_as_float(v2.y & 0xFFFF0000u);
            aAlo += __uint_as_float(v3.x << 16); aAhi += __uint_as_float(v3.x & 0xFFFF0000u);
            aBlo += __uint_as_float(v3.y << 16); aBhi += __uint_as_float(v3.y & 0xFFFF0000u);
        }
        for (; k < hi2; ++k) {
            int i0 = perm[k];
            uint2 v0 = m2[(size_t)(chunk + i0) * 8 + j];
            aAlo += __uint_as_float(v0.x << 16); aAhi += __uint_as_float(v0.x & 0xFFFF0000u);
            aBlo += __uint_as_float(v0.y << 16); aBhi += __uint_as_float(v0.y & 0xFFFF0000u);
        }
        __syncthreads();                        // perm reused next chunk
    }

    int node = bin * BINSZ + g;
    if (node < N) {
        float2 lo2; lo2.x = aAlo; lo2.y = aBlo;
        float2 hi2v; hi2v.x = aAhi; hi2v.y = aBhi;
        *reinterpret_cast<float2*>(&out[(size_t)node * F + 2 * j])      = lo2;
        *reinterpret_cast<float2*>(&out[(size_t)node * F + 16 + 2 * j]) = hi2v;
    }
}

// ====================== FALLBACK 1 (R3 path): cell sort + global atomics ====
__global__ __launch_bounds__(256) void hist_kernel(
    const float* __restrict__ attr, int E, int* __restrict__ counts)
{
    __shared__ int hh[9];
    int b = blockIdx.x, t = threadIdx.x;
    if (t < 9) hh[t] = 0;
    __syncthreads();
    int start = b * OSCH, end = min(start + OSCH, E);
    for (int e = start + t; e < end; e += 256) {
        float2 a = reinterpret_cast<const float2*>(attr)[e];
        float tx = fminf(fmaxf((a.x + 1.0f) * 1.5f, 0.f), 3.f);
        float ty = fminf(fmaxf((a.y + 1.0f) * 1.5f, 0.f), 3.f);
        atomicAdd(&hh[min((int)tx, 2) * 3 + min((int)ty, 2)], 1);
    }
    __syncthreads();
    if (t < 9) counts[b * 9 + t] = hh[t];
}

__global__ __launch_bounds__(512) void scan_kernel(
    int* __restrict__ ws, int* __restrict__ counts, int nblk)
{
    __shared__ int s[OMAXNBLK * 9];
    __shared__ int tot[9];
    __shared__ int coff[9];
    int n = nblk * 9;
    for (int i = threadIdx.x; i < n; i += 512) s[i] = counts[i];
    __syncthreads();
    if (threadIdx.x < 9) {
        int c = threadIdx.x, run = 0;
        for (int b = 0; b < nblk; ++b) {
            int v = s[b * 9 + c];
            s[b * 9 + c] = run;
            run += v;
        }
        tot[c] = run;
    }
    __syncthreads();
    if (threadIdx.x == 0) {
        int off = 0, boff = 0;
        for (int c = 0; c < 9; ++c) {
            ws[c] = off;  coff[c] = off;
            ws[16 + c] = boff;
            off  += tot[c];
            boff += (tot[c] + EPB - 1) / EPB;
        }
        ws[9] = off;
        ws[16 + 9] = boff;
    }
    __syncthreads();
    for (int i = threadIdx.x; i < n; i += 512)
        counts[i] = s[i] + coff[i % 9];
}

__global__ __launch_bounds__(256) void scatter_kernel(
    const float* __restrict__ attr, int E,
    const int* __restrict__ bases, int* __restrict__ sorted)
{
    __shared__ int cur[9];
    int b = blockIdx.x, t = threadIdx.x;
    if (t < 9) cur[t] = bases[b * 9 + t];
    __syncthreads();
    int start = b * OSCH, end = min(start + OSCH, E);
    for (int e = start + t; e < end; e += 256) {
        float2 a = reinterpret_cast<const float2*>(attr)[e];
        float tx = fminf(fmaxf((a.x + 1.0f) * 1.5f, 0.f), 3.f);
        float ty = fminf(fmaxf((a.y + 1.0f) * 1.5f, 0.f), 3.f);
        int c = min((int)tx, 2) * 3 + min((int)ty, 2);
        int pos = atomicAdd(&cur[c], 1);
        sorted[pos] = e;
    }
}

__global__ __launch_bounds__(256) void bconv_mfma(
    const float* __restrict__ x_j, const int* __restrict__ ei,
    const float* __restrict__ attr, const float* __restrict__ weight,
    const int* __restrict__ ws, const int* __restrict__ sorted,
    float* __restrict__ out, int E)
{
    int b = blockIdx.x;
    const int* blkoff = ws + 16;
    if (b >= blkoff[9]) return;
    int c = 0;
    #pragma unroll
    for (int q = 1; q < 9; ++q) c += (b >= blkoff[q]) ? 1 : 0;
    int kx0 = c / 3, ky0 = c - 3 * (c / 3);
    int local  = b - blkoff[c];
    int cstart = ws[c], cend = ws[c + 1];
    int pstart = cstart + local * EPB;
    int pend   = min(pstart + EPB, cend);

    int t = threadIdx.x;
    int wid = t >> 6, lane = t & 63;
    int row16 = lane & 15, hi = lane >> 4;

    short8 wb[4][2];
    #pragma unroll
    for (int kk = 0; kk < 4; ++kk) {
        int ks = (kx0 + (kk >> 1)) * NB + (ky0 + (kk & 1));
        const float* wp = weight + (size_t)ks * F * F;
        #pragma unroll
        for (int n = 0; n < 2; ++n) {
            short8 v;
            #pragma unroll
            for (int j = 0; j < 8; ++j)
                v[j] = f2bf(wp[(8 * hi + j) * F + row16 + 16 * n]);
            wb[kk][n] = v;
        }
    }

    int wstart = pstart + wid * (EPB / 4);
    int wend   = min(wstart + (EPB / 4), pend);
    if (wstart >= wend) return;

    int ntiles = (wend - wstart + 15) >> 4;
    for (int tt = 0; tt < ntiles; ++tt) {
        int p = wstart + tt * 16 + row16;
        bool v = p < wend;
        int pp = v ? p : wstart;
        int e  = sorted[pp];
        int dst = ei[e];
        int srcn = ei[E + e];
        float2 a = reinterpret_cast<const float2*>(attr)[e];
        const float4* xr = reinterpret_cast<const float4*>(x_j + (size_t)srcn * F);
        float4 fa = xr[2 * hi];
        float4 fb = xr[2 * hi + 1];

        float fx = (a.x + 1.0f) * 1.5f - (float)kx0;
        float fy = (a.y + 1.0f) * 1.5f - (float)ky0;
        float vs = v ? 1.f : 0.f;
        float bx0 = (1.f - fx) * vs, bx1 = fx * vs;
        float bc[4] = { bx0 * (1.f - fy), bx0 * fy, bx1 * (1.f - fy), bx1 * fy };

        f32x4 a0 = {0,0,0,0}, a1 = {0,0,0,0};
        #pragma unroll
        for (int kk = 0; kk < 4; ++kk) {
            float s = bc[kk];
            uint4v u;
            u[0] = pk2(fa.x * s, fa.y * s);
            u[1] = pk2(fa.z * s, fa.w * s);
            u[2] = pk2(fb.x * s, fb.y * s);
            u[3] = pk2(fb.z * s, fb.w * s);
            short8 av = __builtin_bit_cast(short8, u);
            a0 = __builtin_amdgcn_mfma_f32_16x16x32_bf16(av, wb[kk][0], a0, 0, 0, 0);
            a1 = __builtin_amdgcn_mfma_f32_16x16x32_bf16(av, wb[kk][1], a1, 0, 0, 0);
        }
        #pragma unroll
        for (int r = 0; r < 4; ++r) {
            int d = __shfl(v ? dst : -1, 4 * hi + r, 64);
            if (d >= 0) {
                atomicAdd(&out[(size_t)d * F + row16],      a0[r]);
                atomicAdd(&out[(size_t)d * F + 16 + row16], a1[r]);
            }
        }
    }
}

// ====================== FALLBACK 2: f32 VALU path ===========================
__global__ __launch_bounds__(256) void bconv_fallback(
    const float* __restrict__ x_j, const int* __restrict__ ei,
    const float* __restrict__ attr, const float* __restrict__ weight,
    float* __restrict__ out, int E)
{
    __shared__ float wl[16 * F * F];
    __shared__ float featl[8][F];
    for (int idx = threadIdx.x; idx < 4096; idx += 256)
        reinterpret_cast<float4*>(wl)[idx] = reinterpret_cast<const float4*>(weight)[idx];
    __syncthreads();

    int lane = threadIdx.x & 31, eslot = threadIdx.x >> 5;
    for (int p = blockIdx.x * 8 + eslot; p < E; p += gridDim.x * 8) {
        int dst = ei[p], srcn = ei[E + p];
        float ax = attr[2 * p], ay = attr[2 * p + 1];
        featl[eslot][lane] = x_j[(size_t)srcn * F + lane];
        float tx = (ax + 1.0f) * 1.5f, ty = (ay + 1.0f) * 1.5f;
        int kx0 = min(max((int)tx, 0), 2), ky0 = min(max((int)ty, 0), 2);
        float fx = tx - kx0, fy = ty - ky0;
        float bcv[4] = { (1.0f - fx) * (1.0f - fy), (1.0f - fx) * fy,
                         fx * (1.0f - fy), fx * fy };
        float msg = 0.f;
        const float4* f4 = reinterpret_cast<const float4*>(&featl[eslot][0]);
        #pragma unroll
        for (int kk = 0; kk < 4; ++kk) {
            int k = (kx0 + (kk >> 1)) * NB + (ky0 + (kk & 1));
            const float* wk = wl + k * F * F;
            float a2 = 0.f;
            #pragma unroll
            for (int j = 0; j < 8; ++j) {
                float4 f = f4[j];
                a2 = fmaf(f.x, wk[(4 * j + 0) * F + lane], a2);
                a2 = fmaf(f.y, wk[(4 * j + 1) * F + lane], a2);
                a2 = fmaf(f.z, wk[(4 * j + 2) * F + lane], a2);
                a2 = fmaf(f.w, wk[(4 * j + 3) * F + lane], a2);
            }
            msg = fmaf(bcv[kk], a2, msg);
        }
        atomicAdd(&out[(size_t)dst * F + lane], msg);
    }
}

extern "C" void kernel_launch(void* const* d_in, const int* in_sizes, int n_in,
                              void* d_out, int out_size, void* d_ws, size_t ws_size,
                              hipStream_t stream) {
    const float* x_j    = (const float*)d_in[1];
    const int*   ei     = (const int*)d_in[2];
    const float* attr   = (const float*)d_in[3];
    const float* weight = (const float*)d_in[4];
    float* out = (float*)d_out;
    int E = in_sizes[2] / 2;
    int N = in_sizes[0] / F;

    int nbin = (N + BINSZ - 1) >> BINSH;

    // --- new-path ws layout (ints) ---
    int o_bincnt   = 0;                       // nbin
    int o_cellcnt  = o_bincnt + nbin;         // 9   (memset covers bincnt+cellcnt)
    int o_binbase  = o_cellcnt + 9;           // nbin+1
    int o_bincur   = o_binbase + nbin + 1;    // nbin
    int o_cellbase = o_bincur + nbin;         // 10
    int o_cellcur  = o_cellbase + 10;         // 9
    int o_blkoff   = o_cellcur + 9;           // 10
    int o_wbf      = (o_blkoff + 10 + 3) & ~3;          // 8192 ints
    int o_dloc     = o_wbf + 8192;                      // ceil(E/4) ints
    int o_cellrec  = (o_dloc + (E + 3) / 4 + 3) & ~3;   // 4E ints (uint4)
    size_t o_msg   = (size_t)((o_cellrec + 4 * (size_t)E + 3) & ~3);
    size_t need_new = (o_msg + 16 * (size_t)E) * sizeof(int);   // bf16 rows: 64 B/edge

    // --- old-path ws layout ---
    int nblk_sort = (E + OSCH - 1) / OSCH;
    int sorted_off = 32 + ((nblk_sort * 9 + 15) & ~15);
    size_t need_old = (size_t)(sorted_off + E) * sizeof(int);

    if (nbin <= MAXBIN && N <= 65536 && E < (1 << 24) && ws_size >= need_new) {
        int* ws = (int*)d_ws;
        short* wbf = (short*)(ws + o_wbf);
        unsigned char* dloc8 = (unsigned char*)(ws + o_dloc);
        uint4* cellrec = (uint4*)(ws + o_cellrec);
        unsigned* msg = (unsigned*)(ws + o_msg);

        hipMemsetAsync(ws, 0, (size_t)(nbin + 9) * sizeof(int), stream);
        w_prep<<<64, 256, 0, stream>>>(weight, wbf);
        h2_kernel<<<256, 256, 0, stream>>>(ei, attr, E, nbin,
                                           ws + o_bincnt, ws + o_cellcnt);
        scan2_kernel<<<1, 256, 0, stream>>>(ws + o_bincnt, ws + o_binbase,
                                            ws + o_bincur, ws + o_cellcnt,
                                            ws + o_cellbase, ws + o_cellcur,
                                            ws + o_blkoff, nbin);
        scat2_kernel<<<(E + SCH - 1) / SCH, 256, 0, stream>>>(
            ei, attr, E, nbin, ws + o_bincur, ws + o_cellcur, cellrec, dloc8);
        int nblkA = (E + EPB - 1) / EPB + 9;
        bconv_msg<<<nblkA, 256, 0, stream>>>(x_j, wbf, ws + o_cellbase,
                                             ws + o_blkoff, cellrec, msg);
        bconv_reduce<<<nbin, 256, 0, stream>>>(msg, dloc8, ws + o_binbase, out, N);
    } else if (nblk_sort <= OMAXNBLK && ws_size >= need_old) {
        hipMemsetAsync(d_out, 0, (size_t)out_size * sizeof(float), stream);
        int* ws      = (int*)d_ws;
        int* counts  = ws + 32;
        int* sorted  = ws + sorted_off;
        hist_kernel<<<nblk_sort, 256, 0, stream>>>(attr, E, counts);
        scan_kernel<<<1, 512, 0, stream>>>(ws, counts, nblk_sort);
        scatter_kernel<<<nblk_sort, 256, 0, stream>>>(attr, E, counts, sorted);
        int nblk_main = (E + EPB - 1) / EPB + 9;
        bconv_mfma<<<nblk_main, 256, 0, stream>>>(x_j, ei, attr, weight, ws, sorted, out, E);
    } else {
        hipMemsetAsync(d_out, 0, (size_t)out_size * sizeof(float), stream);
        bconv_fallback<<<2048, 256, 0, stream>>>(x_j, ei, attr, weight, out, E);
    }
}